// Round 12
// baseline (244.306 us; speedup 1.0000x reference)
//
#include <hip/hip_runtime.h>

typedef __bf16 bf16x8 __attribute__((ext_vector_type(8)));
typedef __bf16 bf16x4 __attribute__((ext_vector_type(4)));
typedef float f32x4 __attribute__((ext_vector_type(4)));

#define MFMA16(a, b, c) __builtin_amdgcn_mfma_f32_16x16x32_bf16((a), (b), (c), 0, 0, 0)

__device__ __forceinline__ void gload_lds16(const void* g, void* l) {
  __builtin_amdgcn_global_load_lds(
      (const __attribute__((address_space(1))) unsigned int*)g,
      (__attribute__((address_space(3))) unsigned int*)l, 16, 0, 0);
}

struct G4 { float4 a, b, c, d; };  // one staged row-slice (16 floats), named members

// ---------------------------------------------------------------------------
// Sliding-window attention. Round-8 math (permuted-fragment swapped QK^T,
// defer-rescale THR=8, exp2, bf16 out) + this round: 3-buffer K/V ring with
// OFF-CHAIN staging — tile kt+1 is converted/written to LDS during tile kt's
// compute (loads issued one full tile earlier), so the inter-barrier chain is
// pure compute. One barrier per tile.
// ---------------------------------------------------------------------------
__global__ __launch_bounds__(256, 2) void attn_kernel(const float* __restrict__ src,
                                                      __bf16* __restrict__ attn_out) {
  const int bid = blockIdx.x;
  const int half = bid & 1;
  const int c = (bid >> 1) & 15;
  const int h = (bid >> 5) & 15;
  const int b = bid >> 9;
  const int tid = threadIdx.x;
  const int w = tid >> 6;
  const int lane = tid & 63;
  const int lg = lane >> 4;
  const int l16 = lane & 15;
  const size_t b4096 = (size_t)b * 4096;

  __shared__ __bf16 Ks[3][64][72];   // K ring, row-major [key][d], pad 72
  __shared__ __bf16 Vt[3][64][72];   // V^T ring [d][key ^ 8*(d>>3)] swizzled

  const int q0 = c * 256 + half * 128 + w * 32;
  const float LOG2E = 1.44269504f;

  bf16x8 qf[2][2];
#pragma unroll
  for (int qfi = 0; qfi < 2; ++qfi)
#pragma unroll
    for (int ks = 0; ks < 2; ++ks) {
      const int row = q0 + qfi * 16 + l16;
      const int d0 = ks * 32 + lg * 8;
      const float* p = src + (b4096 + row) * 1024 + h * 64 + d0;
      bf16x8 v;
#pragma unroll
      for (int j = 0; j < 8; ++j) v[j] = (__bf16)(p[j] * LOG2E);
      qf[qfi][ks] = v;
    }

  int krow[4];
#pragma unroll
  for (int kf = 0; kf < 4; ++kf)
    krow[kf] = ((kf >> 1) << 5) + ((l16 >> 2) << 3) + ((kf & 1) << 2) + (l16 & 3);

  const f32x4 z4 = {0.f, 0.f, 0.f, 0.f};
  float m_run[2], l_run[2];
  f32x4 o[2][4];
#pragma unroll
  for (int qfi = 0; qfi < 2; ++qfi) {
    m_run[qfi] = -6.0e8f;
    l_run[qfi] = 0.f;
#pragma unroll
    for (int df = 0; df < 4; ++df) o[qfi][df] = z4;
  }

  const int stage_key = tid >> 2;
  const int d0a = (tid & 3) * 16;
  const int vcolA = stage_key ^ d0a;
  const int vcolB = stage_key ^ (d0a + 8);
  const int kb00 = c * 256 - 256;

  // issue tile n's global loads (clamped row; OOB zeroed at convert time)
  auto issue = [&](int n) {
    const int kp = kb00 + n * 64 + stage_key;
    const int rc = min(max(kp, 0), 4095);
    const float* p = src + (b4096 + rc) * 1024 + h * 64 + d0a;
    G4 r;
    r.a = *(const float4*)(p + 0);
    r.b = *(const float4*)(p + 4);
    r.c = *(const float4*)(p + 8);
    r.d = *(const float4*)(p + 12);
    return r;
  };
  // convert tile n's regs and write into ring buffer n%3
  auto cw = [&](int n, const G4& g) {
    const int kp = kb00 + n * 64 + stage_key;
    const bool inb = ((unsigned)kp < 4096u);
    bf16x8 kvA, kvB;
    kvA[0] = (__bf16)(inb ? g.a.x : 0.f); kvA[1] = (__bf16)(inb ? g.a.y : 0.f);
    kvA[2] = (__bf16)(inb ? g.a.z : 0.f); kvA[3] = (__bf16)(inb ? g.a.w : 0.f);
    kvA[4] = (__bf16)(inb ? g.b.x : 0.f); kvA[5] = (__bf16)(inb ? g.b.y : 0.f);
    kvA[6] = (__bf16)(inb ? g.b.z : 0.f); kvA[7] = (__bf16)(inb ? g.b.w : 0.f);
    kvB[0] = (__bf16)(inb ? g.c.x : 0.f); kvB[1] = (__bf16)(inb ? g.c.y : 0.f);
    kvB[2] = (__bf16)(inb ? g.c.z : 0.f); kvB[3] = (__bf16)(inb ? g.c.w : 0.f);
    kvB[4] = (__bf16)(inb ? g.d.x : 0.f); kvB[5] = (__bf16)(inb ? g.d.y : 0.f);
    kvB[6] = (__bf16)(inb ? g.d.z : 0.f); kvB[7] = (__bf16)(inb ? g.d.w : 0.f);
    const int bsel = n % 3;
    *(bf16x8*)&Ks[bsel][stage_key][d0a] = kvA;
    *(bf16x8*)&Ks[bsel][stage_key][d0a + 8] = kvB;
#pragma unroll
    for (int j = 0; j < 8; ++j) Vt[bsel][d0a + j][vcolA] = kvA[j];
#pragma unroll
    for (int j = 0; j < 8; ++j) Vt[bsel][d0a + 8 + j][vcolB] = kvB[j];
  };

  // prologue: tile 0 loaded+written; tile 1 loaded into the rolling reg set
  G4 g = issue(0);
  cw(0, g);
  g = issue(1);
  asm volatile("s_waitcnt lgkmcnt(0)" ::: "memory");

  for (int kt = 0; kt < 12; ++kt) {
    const int kbase = kb00 + kt * 64;
    const int cur = kt % 3;
    __builtin_amdgcn_s_barrier();   // publish buf[cur] (written at iter kt-1)
    __builtin_amdgcn_sched_barrier(0);

    const bool skip = (kbase + 63 < 0) | (kbase >= 4096) |
                      (kbase + 63 < q0 - 256) | (kbase > q0 + 31 + 256);

    // ---- S^T = K_perm Q^T (issued first so staging hides under MFMA) ----
    f32x4 s[4][2];
#pragma unroll
    for (int kf = 0; kf < 4; ++kf)
#pragma unroll
      for (int qfi = 0; qfi < 2; ++qfi) s[kf][qfi] = z4;

    if (!skip) {
#pragma unroll
      for (int ks = 0; ks < 2; ++ks) {
        bf16x8 ka[4];
#pragma unroll
        for (int kf = 0; kf < 4; ++kf)
          ka[kf] = *(const bf16x8*)&Ks[cur][krow[kf]][ks * 32 + lg * 8];
#pragma unroll
        for (int kf = 0; kf < 4; ++kf)
#pragma unroll
          for (int qfi = 0; qfi < 2; ++qfi)
            s[kf][qfi] = MFMA16(ka[kf], qf[qfi][ks], s[kf][qfi]);
      }
    }

    // ---- off-chain staging: write tile kt+1, then issue loads for kt+2 ----
    if (kt + 1 < 12) cw(kt + 1, g);
    if (kt + 2 < 12) g = issue(kt + 2);

    if (!skip) {
      const bool needmask = (kbase < 0) | (kbase > 4032) |
                            (kbase < q0 - 225) | (kbase > q0 + 193);
      if (needmask) {
#pragma unroll
        for (int qfi = 0; qfi < 2; ++qfi) {
          const int qp = q0 + qfi * 16 + l16;
#pragma unroll
          for (int kf = 0; kf < 4; ++kf) {
            const int kb0 = kbase + ((kf >> 1) << 5) + 8 * lg + ((kf & 1) << 2);
#pragma unroll
            for (int reg = 0; reg < 4; ++reg) {
              const int kp = kb0 + reg;
              const int rel = kp - qp;
              if (rel > 256 || rel < -256 || kp < 0 || kp >= 4096)
                s[kf][qfi][reg] = -1e9f;
            }
          }
        }
      }

      // ---- online softmax, log2 domain, defer-rescale THR=8 ----
      bf16x4 pb[4][2];
#pragma unroll
      for (int qfi = 0; qfi < 2; ++qfi) {
        float tm = s[0][qfi][0];
#pragma unroll
        for (int kf = 0; kf < 4; ++kf)
#pragma unroll
          for (int reg = 0; reg < 4; ++reg) tm = fmaxf(tm, s[kf][qfi][reg]);
        tm = fmaxf(tm, __shfl_xor(tm, 16, 64));
        tm = fmaxf(tm, __shfl_xor(tm, 32, 64));

        const bool nomax = __all(tm <= m_run[qfi] + 8.f);
        float scl = 1.f;
        if (!nomax) {
          const float mn = fmaxf(m_run[qfi], tm);
          scl = exp2f(m_run[qfi] - mn);
          m_run[qfi] = mn;
#pragma unroll
          for (int df = 0; df < 4; ++df)
#pragma unroll
            for (int reg = 0; reg < 4; ++reg) o[qfi][df][reg] *= scl;
        }
        const float mn = m_run[qfi];

        float rs = 0.f;
#pragma unroll
        for (int kf = 0; kf < 4; ++kf) {
          bf16x4 pv;
#pragma unroll
          for (int reg = 0; reg < 4; ++reg) {
            const float p = exp2f(s[kf][qfi][reg] - mn);
            rs += p;
            pv[reg] = (__bf16)p;
          }
          pb[kf][qfi] = pv;
        }
        rs += __shfl_xor(rs, 16, 64);
        rs += __shfl_xor(rs, 32, 64);
        l_run[qfi] = l_run[qfi] * scl + rs;
      }

      // ---- O^T += V^T P ----
#pragma unroll
      for (int ks2 = 0; ks2 < 2; ++ks2) {
        bf16x8 av[4];
#pragma unroll
        for (int df = 0; df < 4; ++df) {
          const int d = df * 16 + l16;
          const int blk = (ks2 * 4 + lg) ^ (d >> 3);
          av[df] = *(const bf16x8*)&Vt[cur][d][blk * 8];
        }
#pragma unroll
        for (int qfi = 0; qfi < 2; ++qfi) {
          const bf16x8 bq = __builtin_shufflevector(pb[2 * ks2][qfi], pb[2 * ks2 + 1][qfi],
                                                    0, 1, 2, 3, 4, 5, 6, 7);
#pragma unroll
          for (int df = 0; df < 4; ++df)
            o[qfi][df] = MFMA16(av[df], bq, o[qfi][df]);
        }
      }
    }

    asm volatile("s_waitcnt lgkmcnt(0)" ::: "memory");  // drain our ds_writes
  }

#pragma unroll
  for (int qfi = 0; qfi < 2; ++qfi) {
    const float inv = 1.0f / l_run[qfi];
    const int qp = q0 + qfi * 16 + l16;
    __bf16* dst = attn_out + (b4096 + qp) * 1024 + h * 64 + lg * 4;
#pragma unroll
    for (int df = 0; df < 4; ++df) {
      bf16x4 y;
      y[0] = (__bf16)(o[qfi][df][0] * inv);
      y[1] = (__bf16)(o[qfi][df][1] * inv);
      y[2] = (__bf16)(o[qfi][df][2] * inv);
      y[3] = (__bf16)(o[qfi][df][3] * inv);
      *(bf16x4*)&dst[df * 16] = y;
    }
  }
}

// ---------------------------------------------------------------------------
// NT GEMM — round-6 body (best measured), bf16 split-K out.
// BM=BN=256, BK=64, 8 waves (2M x 4N), per-wave 128x64. 2-buffer LDS,
// K-half staging, counted vmcnt(4), 2 regions per K-tile.
// ---------------------------------------------------------------------------
template <int MODE>
__global__ __launch_bounds__(512, 2) void gemm8p(const __bf16* __restrict__ A,
                                                 const __bf16* __restrict__ Bt,
                                                 const float* __restrict__ bias,
                                                 __bf16* __restrict__ out,
                                                 size_t ksplit_stride,
                                                 int M, int N, int Kstride, int Klen) {
  __shared__ char smem[131072];
  const int tid = threadIdx.x;
  const int w = tid >> 6;
  const int lane = tid & 63;
  const int lg = lane >> 4;
  const int l16 = lane & 15;
  const int wr = w >> 2;
  const int wc = w & 3;

  const int nbn = N >> 8;
  const int x = ((int)blockIdx.x & 7) * ((int)gridDim.x >> 3) + ((int)blockIdx.x >> 3);
  const long bm = (long)(x / nbn) * 256;
  const long bn = (long)(x % nbn) * 256;
  const long koff = (long)blockIdx.y * Klen;
  out += (size_t)blockIdx.y * ksplit_stride;

  const f32x4 z4 = {0.f, 0.f, 0.f, 0.f};
  f32x4 acc[8][4];
#pragma unroll
  for (int i = 0; i < 8; ++i)
#pragma unroll
    for (int j = 0; j < 4; ++j) acc[i][j] = z4;

  const int srow = tid >> 2;
  const int g0 = (tid & 3) ^ ((tid >> 3) & 3);
  const __bf16* Ag = A + (size_t)(bm + srow) * Kstride + koff + g0 * 8;
  const __bf16* Bg = Bt + (size_t)(bn + srow) * Kstride + koff + g0 * 8;

  auto stage = [&](int kt, int osel, int isB, int khalf) {
    const __bf16* src = (isB ? Bg : Ag) + (size_t)kt * 64 + khalf * 32;
    char* dst = smem + (isB ? 65536 : 0) + osel * 32768 + khalf * 16384 + (w << 10);
    gload_lds16(src, dst);
    gload_lds16(src + (size_t)128 * Kstride, dst + 8192);
  };

  const int lslot = (lg ^ ((l16 >> 1) & 3)) << 4;
  const char* pA = smem + (wr * 128 + l16) * 64 + lslot;
  const char* pB = smem + 65536 + (wc * 64 + l16) * 64 + lslot;
  auto rdA = [&](int sel, int rf, int ks) {
    return *(const bf16x8*)(pA + sel * 32768 + ks * 16384 + rf * 1024);
  };
  auto rdB = [&](int sel, int cf, int ks) {
    return *(const bf16x8*)(pB + sel * 32768 + ks * 16384 + cf * 1024);
  };

  const int NT = Klen >> 6;

  stage(0, 0, 0, 0);
  stage(0, 0, 1, 0);
  stage(0, 0, 0, 1);
  stage(0, 0, 1, 1);
  asm volatile("s_waitcnt vmcnt(4)" ::: "memory");
  __builtin_amdgcn_s_barrier();
  __builtin_amdgcn_sched_barrier(0);

  for (int t = 0; t < NT; ++t) {
    const int sel = t & 1, osel = sel ^ 1;
    const bool st = (t + 1) < NT;
    bf16x8 af[8], bf[4];

#pragma unroll
    for (int rf = 0; rf < 8; ++rf) af[rf] = rdA(sel, rf, 0);
#pragma unroll
    for (int cf = 0; cf < 4; ++cf) bf[cf] = rdB(sel, cf, 0);
    if (st) { stage(t + 1, osel, 0, 0); stage(t + 1, osel, 1, 0); }
    __builtin_amdgcn_s_setprio(1);
#pragma unroll
    for (int rf = 0; rf < 8; ++rf)
#pragma unroll
      for (int cf = 0; cf < 4; ++cf)
        acc[rf][cf] = MFMA16(af[rf], bf[cf], acc[rf][cf]);
    __builtin_amdgcn_s_setprio(0);
    if (st) asm volatile("s_waitcnt vmcnt(4)" ::: "memory");
    else    asm volatile("s_waitcnt vmcnt(0)" ::: "memory");
    __builtin_amdgcn_s_barrier();
    __builtin_amdgcn_sched_barrier(0);

#pragma unroll
    for (int rf = 0; rf < 8; ++rf) af[rf] = rdA(sel, rf, 1);
#pragma unroll
    for (int cf = 0; cf < 4; ++cf) bf[cf] = rdB(sel, cf, 1);
    if (st) { stage(t + 1, osel, 0, 1); stage(t + 1, osel, 1, 1); }
    __builtin_amdgcn_s_setprio(1);
#pragma unroll
    for (int rf = 0; rf < 8; ++rf)
#pragma unroll
      for (int cf = 0; cf < 4; ++cf)
        acc[rf][cf] = MFMA16(af[rf], bf[cf], acc[rf][cf]);
    __builtin_amdgcn_s_setprio(0);
    if (st) asm volatile("s_waitcnt vmcnt(4)" ::: "memory");
    __builtin_amdgcn_s_barrier();
    __builtin_amdgcn_sched_barrier(0);
  }

  float bv[4];
  if (MODE == 0) {
#pragma unroll
    for (int cf = 0; cf < 4; ++cf) bv[cf] = bias[bn + wc * 64 + cf * 16 + l16];
  }
#pragma unroll
  for (int rf = 0; rf < 8; ++rf)
#pragma unroll
    for (int reg = 0; reg < 4; ++reg) {
      const long row = bm + wr * 128 + rf * 16 + lg * 4 + reg;
#pragma unroll
      for (int cf = 0; cf < 4; ++cf) {
        const long col = bn + wc * 64 + cf * 16 + l16;
        if (MODE == 0) {
          out[row * N + col] = (__bf16)fmaxf(acc[rf][cf][reg] + bv[cf], 0.f);
        } else {
          out[row * N + col] = (__bf16)acc[rf][cf][reg];
        }
      }
    }
}

// ---------------------------------------------------------------------------
__global__ __launch_bounds__(256) void transpose_cvt(const float* __restrict__ in,
                                                     __bf16* __restrict__ out,
                                                     int R, int C) {
  __shared__ float tile[64][65];
  const long r0 = (long)blockIdx.y * 64;
  const long c0 = (long)blockIdx.x * 64;
  const int t = threadIdx.x;
  const int tr = t >> 6;
  const int tc = t & 63;
#pragma unroll
  for (int i = 0; i < 16; ++i) {
    const int r = tr * 16 + i;
    tile[r][tc] = in[(r0 + r) * C + c0 + tc];
  }
  __syncthreads();
#pragma unroll
  for (int i = 0; i < 16; ++i) {
    const int cc = tr * 16 + i;
    out[(c0 + cc) * (long)R + r0 + tc] = (__bf16)tile[tc][cc];
  }
}

// ---------------------------------------------------------------------------
__global__ __launch_bounds__(256) void ln1_kernel(const float* __restrict__ src,
                                                  const __bf16* __restrict__ attn,
                                                  const float* __restrict__ g,
                                                  const float* __restrict__ bta,
                                                  __bf16* __restrict__ xb) {
  const long r = blockIdx.x;
  const int t = threadIdx.x;
  const float4 a = *(const float4*)&src[r * 1024 + t * 4];
  const bf16x4 cc = *(const bf16x4*)&attn[r * 1024 + t * 4];
  float v[4] = {a.x + (float)cc[0], a.y + (float)cc[1],
                a.z + (float)cc[2], a.w + (float)cc[3]};
  float s = v[0] + v[1] + v[2] + v[3];
  float s2 = v[0] * v[0] + v[1] * v[1] + v[2] * v[2] + v[3] * v[3];
#pragma unroll
  for (int off = 32; off >= 1; off >>= 1) {
    s += __shfl_xor(s, off, 64);
    s2 += __shfl_xor(s2, off, 64);
  }
  __shared__ float red[8];
  if ((t & 63) == 0) { red[t >> 6] = s; red[(t >> 6) + 4] = s2; }
  __syncthreads();
  s = red[0] + red[1] + red[2] + red[3];
  s2 = red[4] + red[5] + red[6] + red[7];
  const float mu = s * (1.f / 1024.f);
  const float var = s2 * (1.f / 1024.f) - mu * mu;
  const float rstd = rsqrtf(var + 1e-5f);
  const float4 gv = *(const float4*)&g[t * 4];
  const float4 bv = *(const float4*)&bta[t * 4];
  bf16x4 y;
  y[0] = (__bf16)((v[0] - mu) * rstd * gv.x + bv.x);
  y[1] = (__bf16)((v[1] - mu) * rstd * gv.y + bv.y);
  y[2] = (__bf16)((v[2] - mu) * rstd * gv.z + bv.z);
  y[3] = (__bf16)((v[3] - mu) * rstd * gv.w + bv.w);
  *(bf16x4*)&xb[r * 1024 + t * 4] = y;
}

__global__ __launch_bounds__(256) void ln2_kernel(const __bf16* __restrict__ xb,
                                                  const __bf16* __restrict__ f0,
                                                  const __bf16* __restrict__ f1,
                                                  const float* __restrict__ b2,
                                                  const float* __restrict__ g,
                                                  const float* __restrict__ bta,
                                                  float* __restrict__ out) {
  const long r = blockIdx.x;
  const int t = threadIdx.x;
  const bf16x4 xv = *(const bf16x4*)&xb[r * 1024 + t * 4];
  const bf16x4 f0v = *(const bf16x4*)&f0[r * 1024 + t * 4];
  const bf16x4 f1v = *(const bf16x4*)&f1[r * 1024 + t * 4];
  const float4 b2v = *(const float4*)&b2[t * 4];
  float v[4];
#pragma unroll
  for (int i = 0; i < 4; ++i)
    v[i] = (float)xv[i] + (float)f0v[i] + (float)f1v[i] +
           ((const float*)&b2v)[i];
  float s = v[0] + v[1] + v[2] + v[3];
  float s2 = v[0] * v[0] + v[1] * v[1] + v[2] * v[2] + v[3] * v[3];
#pragma unroll
  for (int off = 32; off >= 1; off >>= 1) {
    s += __shfl_xor(s, off, 64);
    s2 += __shfl_xor(s2, off, 64);
  }
  __shared__ float red[8];
  if ((t & 63) == 0) { red[t >> 6] = s; red[(t >> 6) + 4] = s2; }
  __syncthreads();
  s = red[0] + red[1] + red[2] + red[3];
  s2 = red[4] + red[5] + red[6] + red[7];
  const float mu = s * (1.f / 1024.f);
  const float var = s2 * (1.f / 1024.f) - mu * mu;
  const float rstd = rsqrtf(var + 1e-5f);
  const float4 gv = *(const float4*)&g[t * 4];
  const float4 bv = *(const float4*)&bta[t * 4];
  float4 y;
  y.x = (v[0] - mu) * rstd * gv.x + bv.x;
  y.y = (v[1] - mu) * rstd * gv.y + bv.y;
  y.z = (v[2] - mu) * rstd * gv.z + bv.z;
  y.w = (v[3] - mu) * rstd * gv.w + bv.w;
  *(float4*)&out[r * 1024 + t * 4] = y;
}

// ---------------------------------------------------------------------------
extern "C" void kernel_launch(void* const* d_in, const int* in_sizes, int n_in,
                              void* d_out, int out_size, void* d_ws, size_t ws_size,
                              hipStream_t stream) {
  const float* src = (const float*)d_in[0];
  const float* ln1_g = (const float*)d_in[1];
  const float* ln1_b = (const float*)d_in[2];
  const float* ln2_g = (const float*)d_in[3];
  const float* ln2_b = (const float*)d_in[4];
  const float* W1 = (const float*)d_in[5];
  const float* b1 = (const float*)d_in[6];
  const float* W2 = (const float*)d_in[7];
  const float* b2 = (const float*)d_in[8];
  float* out = (float*)d_out;
  char* ws = (char*)d_ws;

  const size_t MB = 1048576;
  __bf16* xb = (__bf16*)ws;                  // @0   16 MB
  __bf16* attn_b = (__bf16*)(ws + 16 * MB);  // @16  16 MB (also ff partial 0)
  __bf16* ffb = attn_b;
  __bf16* ff1b = (__bf16*)(ws + 32 * MB);    // @32  16 MB (ff partial 1)
  __bf16* w1t = (__bf16*)(ws + 48 * MB);     // @48  8 MB
  __bf16* w2t = (__bf16*)(ws + 56 * MB);     // @56  8 MB
  __bf16* hbuf = (__bf16*)(ws + 64 * MB);    // @64  Mc*4096*2 B

  int Mc = 8192;
  while (Mc > 512 && 64 * MB + (size_t)Mc * 8192 > ws_size) Mc >>= 1;

  transpose_cvt<<<dim3(4096 / 64, 1024 / 64), 256, 0, stream>>>(W1, w1t, 1024, 4096);
  transpose_cvt<<<dim3(1024 / 64, 4096 / 64), 256, 0, stream>>>(W2, w2t, 4096, 1024);
  attn_kernel<<<1024, 256, 0, stream>>>(src, attn_b);
  ln1_kernel<<<8192, 256, 0, stream>>>(src, attn_b, ln1_g, ln1_b, xb);
  for (int m0 = 0; m0 < 8192; m0 += Mc) {
    gemm8p<0><<<dim3((Mc / 256) * (4096 / 256), 1), 512, 0, stream>>>(
        xb + (size_t)m0 * 1024, w1t, b1, hbuf, 0, Mc, 4096, 1024, 1024);
    gemm8p<1><<<dim3((Mc / 256) * (1024 / 256), 2), 512, 0, stream>>>(
        hbuf, w2t, nullptr, ffb + (size_t)m0 * 1024, (size_t)8192 * 1024,
        Mc, 1024, 4096, 2048);
  }
  ln2_kernel<<<8192, 256, 0, stream>>>(xb, ffb, ff1b, b2, ln2_g, ln2_b, out);
}

// Round 13
// 230.455 us; speedup vs baseline: 1.0601x; 1.0601x over previous
//
#include <hip/hip_runtime.h>

typedef __bf16 bf16x8 __attribute__((ext_vector_type(8)));
typedef __bf16 bf16x4 __attribute__((ext_vector_type(4)));
typedef float f32x4 __attribute__((ext_vector_type(4)));

#define MFMA16(a, b, c) __builtin_amdgcn_mfma_f32_16x16x32_bf16((a), (b), (c), 0, 0, 0)

__device__ __forceinline__ void gload_lds16(const void* g, void* l) {
  __builtin_amdgcn_global_load_lds(
      (const __attribute__((address_space(1))) unsigned int*)g,
      (__attribute__((address_space(3))) unsigned int*)l, 16, 0, 0);
}

// ---------------------------------------------------------------------------
// Sliding-window attention (round 8/11 exact — best measured config).
// ---------------------------------------------------------------------------
__global__ __launch_bounds__(256, 2) void attn_kernel(const float* __restrict__ src,
                                                      __bf16* __restrict__ attn_out) {
  const int bid = blockIdx.x;
  const int half = bid & 1;
  const int c = (bid >> 1) & 15;
  const int h = (bid >> 5) & 15;
  const int b = bid >> 9;
  const int tid = threadIdx.x;
  const int w = tid >> 6;
  const int lane = tid & 63;
  const int lg = lane >> 4;
  const int l16 = lane & 15;
  const size_t b4096 = (size_t)b * 4096;

  __shared__ __bf16 Ks[2][64][72];
  __shared__ __bf16 Vt[2][64][72];

  const int q0 = c * 256 + half * 128 + w * 32;
  const float LOG2E = 1.44269504f;

  bf16x8 qf[2][2];
#pragma unroll
  for (int qfi = 0; qfi < 2; ++qfi)
#pragma unroll
    for (int ks = 0; ks < 2; ++ks) {
      const int row = q0 + qfi * 16 + l16;
      const int d0 = ks * 32 + lg * 8;
      const float* p = src + (b4096 + row) * 1024 + h * 64 + d0;
      bf16x8 v;
#pragma unroll
      for (int j = 0; j < 8; ++j) v[j] = (__bf16)(p[j] * LOG2E);
      qf[qfi][ks] = v;
    }

  int krow[4];
#pragma unroll
  for (int kf = 0; kf < 4; ++kf)
    krow[kf] = ((kf >> 1) << 5) + ((l16 >> 2) << 3) + ((kf & 1) << 2) + (l16 & 3);

  const f32x4 z4 = {0.f, 0.f, 0.f, 0.f};
  float m_run[2], l_run[2];
  f32x4 o[2][4];
#pragma unroll
  for (int qfi = 0; qfi < 2; ++qfi) {
    m_run[qfi] = -6.0e8f;
    l_run[qfi] = 0.f;
#pragma unroll
    for (int df = 0; df < 4; ++df) o[qfi][df] = z4;
  }

  const int stage_key = tid >> 2;
  const int d0a = (tid & 3) * 16;
  const int vcolA = stage_key ^ d0a;
  const int vcolB = stage_key ^ (d0a + 8);

  int kpos = c * 256 - 256 + stage_key;
  float4 g4[4];
  {
    const int rc = min(max(kpos, 0), 4095);
    const float* p = src + (b4096 + rc) * 1024 + h * 64 + d0a;
#pragma unroll
    for (int i = 0; i < 4; ++i) g4[i] = *(const float4*)(p + i * 4);
  }

  for (int kt = 0; kt < 12; ++kt) {
    const int kbase = c * 256 - 256 + kt * 64;
    const int cur = kt & 1;
    bf16x8 kvA, kvB;
    const bool inb = ((unsigned)kpos < 4096u);
    kvA[0] = (__bf16)(inb ? g4[0].x : 0.f); kvA[1] = (__bf16)(inb ? g4[0].y : 0.f);
    kvA[2] = (__bf16)(inb ? g4[0].z : 0.f); kvA[3] = (__bf16)(inb ? g4[0].w : 0.f);
    kvA[4] = (__bf16)(inb ? g4[1].x : 0.f); kvA[5] = (__bf16)(inb ? g4[1].y : 0.f);
    kvA[6] = (__bf16)(inb ? g4[1].z : 0.f); kvA[7] = (__bf16)(inb ? g4[1].w : 0.f);
    kvB[0] = (__bf16)(inb ? g4[2].x : 0.f); kvB[1] = (__bf16)(inb ? g4[2].y : 0.f);
    kvB[2] = (__bf16)(inb ? g4[2].z : 0.f); kvB[3] = (__bf16)(inb ? g4[2].w : 0.f);
    kvB[4] = (__bf16)(inb ? g4[3].x : 0.f); kvB[5] = (__bf16)(inb ? g4[3].y : 0.f);
    kvB[6] = (__bf16)(inb ? g4[3].z : 0.f); kvB[7] = (__bf16)(inb ? g4[3].w : 0.f);

    *(bf16x8*)&Ks[cur][stage_key][d0a] = kvA;
    *(bf16x8*)&Ks[cur][stage_key][d0a + 8] = kvB;
#pragma unroll
    for (int j = 0; j < 8; ++j) Vt[cur][d0a + j][vcolA] = kvA[j];
#pragma unroll
    for (int j = 0; j < 8; ++j) Vt[cur][d0a + 8 + j][vcolB] = kvB[j];
    asm volatile("s_waitcnt lgkmcnt(0)" ::: "memory");
    __builtin_amdgcn_s_barrier();
    __builtin_amdgcn_sched_barrier(0);

    kpos += 64;
    if (kt < 11) {
      const int rc = min(max(kpos, 0), 4095);
      const float* p = src + (b4096 + rc) * 1024 + h * 64 + d0a;
#pragma unroll
      for (int i = 0; i < 4; ++i) g4[i] = *(const float4*)(p + i * 4);
    }

    const bool skip = (kbase + 63 < 0) | (kbase >= 4096) |
                      (kbase + 63 < q0 - 256) | (kbase > q0 + 31 + 256);
    if (skip) continue;

    f32x4 s[4][2];
#pragma unroll
    for (int kf = 0; kf < 4; ++kf)
#pragma unroll
      for (int qfi = 0; qfi < 2; ++qfi) s[kf][qfi] = z4;

#pragma unroll
    for (int ks = 0; ks < 2; ++ks) {
      bf16x8 ka[4];
#pragma unroll
      for (int kf = 0; kf < 4; ++kf)
        ka[kf] = *(const bf16x8*)&Ks[cur][krow[kf]][ks * 32 + lg * 8];
#pragma unroll
      for (int kf = 0; kf < 4; ++kf)
#pragma unroll
        for (int qfi = 0; qfi < 2; ++qfi)
          s[kf][qfi] = MFMA16(ka[kf], qf[qfi][ks], s[kf][qfi]);
    }

    const bool needmask = (kbase < 0) | (kbase > 4032) |
                          (kbase < q0 - 225) | (kbase > q0 + 193);
    if (needmask) {
#pragma unroll
      for (int qfi = 0; qfi < 2; ++qfi) {
        const int qp = q0 + qfi * 16 + l16;
#pragma unroll
        for (int kf = 0; kf < 4; ++kf) {
          const int kb0 = kbase + ((kf >> 1) << 5) + 8 * lg + ((kf & 1) << 2);
#pragma unroll
          for (int reg = 0; reg < 4; ++reg) {
            const int kp = kb0 + reg;
            const int rel = kp - qp;
            if (rel > 256 || rel < -256 || kp < 0 || kp >= 4096)
              s[kf][qfi][reg] = -1e9f;
          }
        }
      }
    }

    bf16x4 pb[4][2];
#pragma unroll
    for (int qfi = 0; qfi < 2; ++qfi) {
      float tm = s[0][qfi][0];
#pragma unroll
      for (int kf = 0; kf < 4; ++kf)
#pragma unroll
        for (int reg = 0; reg < 4; ++reg) tm = fmaxf(tm, s[kf][qfi][reg]);
      tm = fmaxf(tm, __shfl_xor(tm, 16, 64));
      tm = fmaxf(tm, __shfl_xor(tm, 32, 64));

      const bool nomax = __all(tm <= m_run[qfi] + 8.f);
      float scl = 1.f;
      if (!nomax) {
        const float mn = fmaxf(m_run[qfi], tm);
        scl = exp2f(m_run[qfi] - mn);
        m_run[qfi] = mn;
#pragma unroll
        for (int df = 0; df < 4; ++df)
#pragma unroll
          for (int reg = 0; reg < 4; ++reg) o[qfi][df][reg] *= scl;
      }
      const float mn = m_run[qfi];

      float rs = 0.f;
#pragma unroll
      for (int kf = 0; kf < 4; ++kf) {
        bf16x4 pv;
#pragma unroll
        for (int reg = 0; reg < 4; ++reg) {
          const float p = exp2f(s[kf][qfi][reg] - mn);
          rs += p;
          pv[reg] = (__bf16)p;
        }
        pb[kf][qfi] = pv;
      }
      rs += __shfl_xor(rs, 16, 64);
      rs += __shfl_xor(rs, 32, 64);
      l_run[qfi] = l_run[qfi] * scl + rs;
    }

#pragma unroll
    for (int ks2 = 0; ks2 < 2; ++ks2) {
      bf16x8 av[4];
#pragma unroll
      for (int df = 0; df < 4; ++df) {
        const int d = df * 16 + l16;
        const int blk = (ks2 * 4 + lg) ^ (d >> 3);
        av[df] = *(const bf16x8*)&Vt[cur][d][blk * 8];
      }
#pragma unroll
      for (int qfi = 0; qfi < 2; ++qfi) {
        const bf16x8 bq = __builtin_shufflevector(pb[2 * ks2][qfi], pb[2 * ks2 + 1][qfi],
                                                  0, 1, 2, 3, 4, 5, 6, 7);
#pragma unroll
        for (int df = 0; df < 4; ++df)
          o[qfi][df] = MFMA16(av[df], bq, o[qfi][df]);
      }
    }
  }

#pragma unroll
  for (int qfi = 0; qfi < 2; ++qfi) {
    const float inv = 1.0f / l_run[qfi];
    const int qp = q0 + qfi * 16 + l16;
    __bf16* dst = attn_out + (b4096 + qp) * 1024 + h * 64 + lg * 4;
#pragma unroll
    for (int df = 0; df < 4; ++df) {
      bf16x4 y;
      y[0] = (__bf16)(o[qfi][df][0] * inv);
      y[1] = (__bf16)(o[qfi][df][1] * inv);
      y[2] = (__bf16)(o[qfi][df][2] * inv);
      y[3] = (__bf16)(o[qfi][df][3] * inv);
      *(bf16x4*)&dst[df * 16] = y;
    }
  }
}

// ---------------------------------------------------------------------------
// m201-faithful 8-phase NT GEMM. BM=BN=256, BK=64, 8 waves (2M x 4N,
// per-wave 128x64). 2 K-tiles per iteration (buf0=even, buf1=odd); 8 phases
// of exactly 16 MFMA; reads {12,4,8,0} per K-tile with register-resident
// A/B fragments; one 128x64 half-tile staged per phase (2 gload_lds); counted
// vmcnt(4) at phases 4/8 only (keeps 2 newest half-tiles, retires everything
// the next 4 phases read). LDS 128KB: buf[2] x {A[2][128][64], B[2][128][64]}.
// Swizzle: read byte ^ ((l16&7)<<4), source group g0=(tid&7)^(srow&7).
// ---------------------------------------------------------------------------
template <int MODE>
__global__ __launch_bounds__(512, 2) void gemm8p(const __bf16* __restrict__ A,
                                                 const __bf16* __restrict__ Bt,
                                                 const float* __restrict__ bias,
                                                 __bf16* __restrict__ out,
                                                 size_t ksplit_stride,
                                                 int M, int N, int Kstride, int Klen) {
  __shared__ char smem[131072];
  const int tid = threadIdx.x;
  const int w = tid >> 6;
  const int lane = tid & 63;
  const int lg = lane >> 4;
  const int l16 = lane & 15;
  const int wr = w >> 2;  // 0..1 (M half)
  const int wc = w & 3;   // 0..3 (N quarter)

  const int nbn = N >> 8;
  const int x = ((int)blockIdx.x & 7) * ((int)gridDim.x >> 3) + ((int)blockIdx.x >> 3);
  const long bm = (long)(x / nbn) * 256;
  const long bn = (long)(x % nbn) * 256;
  const long koff = (long)blockIdx.y * Klen;
  out += (size_t)blockIdx.y * ksplit_stride;

  const f32x4 z4 = {0.f, 0.f, 0.f, 0.f};
  f32x4 acc[8][4];
#pragma unroll
  for (int i = 0; i < 8; ++i)
#pragma unroll
    for (int j = 0; j < 4; ++j) acc[i][j] = z4;

  const int srow = tid >> 3;               // 0..63
  const int g0 = (tid & 7) ^ (srow & 7);   // pre-swizzled 16B source group
  const __bf16* Ag = A + (size_t)(bm + srow) * Kstride + koff + g0 * 8;
  const __bf16* Bg = Bt + (size_t)(bn + srow) * Kstride + koff + g0 * 8;
  char* ldst = smem + (w << 10);

  // stage one half-tile: which 0=A0 1=A1 2=B0 3=B1; dest buf = kt&1 (linear)
  auto stage = [&](int kt, int which) {
    const __bf16* s = ((which & 2) ? Bg : Ag) +
                      (size_t)((which & 1) * 128) * Kstride + (size_t)kt * 64;
    char* d = ldst + ((kt & 1) << 16) + ((which & 2) << 14) + ((which & 1) << 14);
    gload_lds16(s, d);
    gload_lds16(s + (size_t)64 * Kstride, d + 8192);
  };

  const unsigned rsw = (unsigned)((l16 & 7) << 4);
  const char* pA = smem + wr * 16384 + l16 * 128;
  const char* pB = smem + 32768 + (wc >> 1) * 16384 + ((wc & 1) * 64 + l16) * 128;
  auto rdA = [&](int sel, int rf, int ks) {
    return *(const bf16x8*)(pA + (sel << 16) + rf * 2048 +
                            ((unsigned)((ks << 6) | (lg << 4)) ^ rsw));
  };
  auto rdB = [&](int sel, int cf, int ks) {
    return *(const bf16x8*)(pB + (sel << 16) + cf * 2048 +
                            ((unsigned)((ks << 6) | (lg << 4)) ^ rsw));
  };

  const int NT = Klen >> 6;  // even (16 or 32)

  // prologue: tile0 all 4 halves + tile1 B halves (12 loads); retire tile0
  stage(0, 0); stage(0, 1); stage(0, 2); stage(0, 3);
  stage(1, 2); stage(1, 3);
  asm volatile("s_waitcnt vmcnt(4)" ::: "memory");
  __builtin_amdgcn_s_barrier();
  __builtin_amdgcn_sched_barrier(0);

  bf16x8 af[4][2], bl[2][2], bh[2][2];

  for (int i = 0; i < (NT >> 1); ++i) {
    const int a = i << 1;
    const int b = a + 1, c2 = a + 2, d2 = a + 3;
    const bool more = (c2 < NT);

#pragma unroll
    for (int sel = 0; sel < 2; ++sel) {  // sel 0: tile a (buf0); sel 1: tile b (buf1)
      const int tnext = sel ? d2 : c2;   // tile whose B we stage in ph3/ph4
      const int anext = sel ? c2 : b;    // tile whose A we stage in ph1/ph2
      const bool stA = sel ? more : true;
      const bool stB = more;

      // ---- ph1: read A rf0-3 + B cf0-1 (12); stage A0(anext); MFMA [0-3][0-1]
#pragma unroll
      for (int rf = 0; rf < 4; ++rf)
#pragma unroll
        for (int ks = 0; ks < 2; ++ks) af[rf][ks] = rdA(sel, rf, ks);
#pragma unroll
      for (int cf = 0; cf < 2; ++cf)
#pragma unroll
        for (int ks = 0; ks < 2; ++ks) bl[cf][ks] = rdB(sel, cf, ks);
      if (stA) stage(anext, 0);
      __builtin_amdgcn_s_barrier();
      asm volatile("s_waitcnt lgkmcnt(0)" ::: "memory");
      __builtin_amdgcn_sched_barrier(0);
      __builtin_amdgcn_s_setprio(1);
#pragma unroll
      for (int rf = 0; rf < 4; ++rf)
#pragma unroll
        for (int cf = 0; cf < 2; ++cf)
#pragma unroll
          for (int ks = 0; ks < 2; ++ks)
            acc[rf][cf] = MFMA16(af[rf][ks], bl[cf][ks], acc[rf][cf]);
      __builtin_amdgcn_s_setprio(0);

      // ---- ph2: read B cf2-3 (4); stage A1(anext); MFMA [0-3][2-3]
#pragma unroll
      for (int cf = 0; cf < 2; ++cf)
#pragma unroll
        for (int ks = 0; ks < 2; ++ks) bh[cf][ks] = rdB(sel, 2 + cf, ks);
      if (stA) stage(anext, 1);
      __builtin_amdgcn_s_barrier();
      asm volatile("s_waitcnt lgkmcnt(0)" ::: "memory");
      __builtin_amdgcn_sched_barrier(0);
      __builtin_amdgcn_s_setprio(1);
#pragma unroll
      for (int rf = 0; rf < 4; ++rf)
#pragma unroll
        for (int cf = 0; cf < 2; ++cf)
#pragma unroll
          for (int ks = 0; ks < 2; ++ks)
            acc[rf][2 + cf] = MFMA16(af[rf][ks], bh[cf][ks], acc[rf][2 + cf]);
      __builtin_amdgcn_s_setprio(0);

      // ---- ph3: read A rf4-7 (8); stage B0(tnext); MFMA [4-7][0-1]
#pragma unroll
      for (int rf = 0; rf < 4; ++rf)
#pragma unroll
        for (int ks = 0; ks < 2; ++ks) af[rf][ks] = rdA(sel, 4 + rf, ks);
      if (stB) stage(tnext, 2);
      __builtin_amdgcn_s_barrier();
      asm volatile("s_waitcnt lgkmcnt(0)" ::: "memory");
      __builtin_amdgcn_sched_barrier(0);
      __builtin_amdgcn_s_setprio(1);
#pragma unroll
      for (int rf = 0; rf < 4; ++rf)
#pragma unroll
        for (int cf = 0; cf < 2; ++cf)
#pragma unroll
          for (int ks = 0; ks < 2; ++ks)
            acc[4 + rf][cf] = MFMA16(af[rf][ks], bl[cf][ks], acc[4 + rf][cf]);
      __builtin_amdgcn_s_setprio(0);

      // ---- ph4: stage B1(tnext); counted vmcnt; barrier; MFMA [4-7][2-3]
      if (stB) {
        stage(tnext, 3);
        asm volatile("s_waitcnt vmcnt(4)" ::: "memory");
      } else {
        asm volatile("s_waitcnt vmcnt(0)" ::: "memory");
      }
      __builtin_amdgcn_s_barrier();
      __builtin_amdgcn_sched_barrier(0);
      __builtin_amdgcn_s_setprio(1);
#pragma unroll
      for (int rf = 0; rf < 4; ++rf)
#pragma unroll
        for (int cf = 0; cf < 2; ++cf)
#pragma unroll
          for (int ks = 0; ks < 2; ++ks)
            acc[4 + rf][2 + cf] = MFMA16(af[rf][ks], bh[cf][ks], acc[4 + rf][2 + cf]);
      __builtin_amdgcn_s_setprio(0);
    }
  }

  float bv[4];
  if (MODE == 0) {
#pragma unroll
    for (int cf = 0; cf < 4; ++cf) bv[cf] = bias[bn + wc * 64 + cf * 16 + l16];
  }
#pragma unroll
  for (int rf = 0; rf < 8; ++rf)
#pragma unroll
    for (int reg = 0; reg < 4; ++reg) {
      const long row = bm + wr * 128 + rf * 16 + lg * 4 + reg;
#pragma unroll
      for (int cf = 0; cf < 4; ++cf) {
        const long col = bn + wc * 64 + cf * 16 + l16;
        if (MODE == 0) {
          out[row * N + col] = (__bf16)fmaxf(acc[rf][cf][reg] + bv[cf], 0.f);
        } else {
          out[row * N + col] = (__bf16)acc[rf][cf][reg];
        }
      }
    }
}

// ---------------------------------------------------------------------------
__global__ __launch_bounds__(256) void transpose_cvt(const float* __restrict__ in,
                                                     __bf16* __restrict__ out,
                                                     int R, int C) {
  __shared__ float tile[64][65];
  const long r0 = (long)blockIdx.y * 64;
  const long c0 = (long)blockIdx.x * 64;
  const int t = threadIdx.x;
  const int tr = t >> 6;
  const int tc = t & 63;
#pragma unroll
  for (int i = 0; i < 16; ++i) {
    const int r = tr * 16 + i;
    tile[r][tc] = in[(r0 + r) * C + c0 + tc];
  }
  __syncthreads();
#pragma unroll
  for (int i = 0; i < 16; ++i) {
    const int cc = tr * 16 + i;
    out[(c0 + cc) * (long)R + r0 + tc] = (__bf16)tile[tc][cc];
  }
}

// ---------------------------------------------------------------------------
__global__ __launch_bounds__(256) void ln1_kernel(const float* __restrict__ src,
                                                  const __bf16* __restrict__ attn,
                                                  const float* __restrict__ g,
                                                  const float* __restrict__ bta,
                                                  __bf16* __restrict__ xb) {
  const long r = blockIdx.x;
  const int t = threadIdx.x;
  const float4 a = *(const float4*)&src[r * 1024 + t * 4];
  const bf16x4 cc = *(const bf16x4*)&attn[r * 1024 + t * 4];
  float v[4] = {a.x + (float)cc[0], a.y + (float)cc[1],
                a.z + (float)cc[2], a.w + (float)cc[3]};
  float s = v[0] + v[1] + v[2] + v[3];
  float s2 = v[0] * v[0] + v[1] * v[1] + v[2] * v[2] + v[3] * v[3];
#pragma unroll
  for (int off = 32; off >= 1; off >>= 1) {
    s += __shfl_xor(s, off, 64);
    s2 += __shfl_xor(s2, off, 64);
  }
  __shared__ float red[8];
  if ((t & 63) == 0) { red[t >> 6] = s; red[(t >> 6) + 4] = s2; }
  __syncthreads();
  s = red[0] + red[1] + red[2] + red[3];
  s2 = red[4] + red[5] + red[6] + red[7];
  const float mu = s * (1.f / 1024.f);
  const float var = s2 * (1.f / 1024.f) - mu * mu;
  const float rstd = rsqrtf(var + 1e-5f);
  const float4 gv = *(const float4*)&g[t * 4];
  const float4 bv = *(const float4*)&bta[t * 4];
  bf16x4 y;
  y[0] = (__bf16)((v[0] - mu) * rstd * gv.x + bv.x);
  y[1] = (__bf16)((v[1] - mu) * rstd * gv.y + bv.y);
  y[2] = (__bf16)((v[2] - mu) * rstd * gv.z + bv.z);
  y[3] = (__bf16)((v[3] - mu) * rstd * gv.w + bv.w);
  *(bf16x4*)&xb[r * 1024 + t * 4] = y;
}

__global__ __launch_bounds__(256) void ln2_kernel(const __bf16* __restrict__ xb,
                                                  const __bf16* __restrict__ f0,
                                                  const __bf16* __restrict__ f1,
                                                  const float* __restrict__ b2,
                                                  const float* __restrict__ g,
                                                  const float* __restrict__ bta,
                                                  float* __restrict__ out) {
  const long r = blockIdx.x;
  const int t = threadIdx.x;
  const bf16x4 xv = *(const bf16x4*)&xb[r * 1024 + t * 4];
  const bf16x4 f0v = *(const bf16x4*)&f0[r * 1024 + t * 4];
  const bf16x4 f1v = *(const bf16x4*)&f1[r * 1024 + t * 4];
  const float4 b2v = *(const float4*)&b2[t * 4];
  float v[4];
#pragma unroll
  for (int i = 0; i < 4; ++i)
    v[i] = (float)xv[i] + (float)f0v[i] + (float)f1v[i] +
           ((const float*)&b2v)[i];
  float s = v[0] + v[1] + v[2] + v[3];
  float s2 = v[0] * v[0] + v[1] * v[1] + v[2] * v[2] + v[3] * v[3];
#pragma unroll
  for (int off = 32; off >= 1; off >>= 1) {
    s += __shfl_xor(s, off, 64);
    s2 += __shfl_xor(s2, off, 64);
  }
  __shared__ float red[8];
  if ((t & 63) == 0) { red[t >> 6] = s; red[(t >> 6) + 4] = s2; }
  __syncthreads();
  s = red[0] + red[1] + red[2] + red[3];
  s2 = red[4] + red[5] + red[6] + red[7];
  const float mu = s * (1.f / 1024.f);
  const float var = s2 * (1.f / 1024.f) - mu * mu;
  const float rstd = rsqrtf(var + 1e-5f);
  const float4 gv = *(const float4*)&g[t * 4];
  const float4 bv = *(const float4*)&bta[t * 4];
  float4 y;
  y.x = (v[0] - mu) * rstd * gv.x + bv.x;
  y.y = (v[1] - mu) * rstd * gv.y + bv.y;
  y.z = (v[2] - mu) * rstd * gv.z + bv.z;
  y.w = (v[3] - mu) * rstd * gv.w + bv.w;
  *(float4*)&out[r * 1024 + t * 4] = y;
}

// ---------------------------------------------------------------------------
extern "C" void kernel_launch(void* const* d_in, const int* in_sizes, int n_in,
                              void* d_out, int out_size, void* d_ws, size_t ws_size,
                              hipStream_t stream) {
  const float* src = (const float*)d_in[0];
  const float* ln1_g = (const float*)d_in[1];
  const float* ln1_b = (const float*)d_in[2];
  const float* ln2_g = (const float*)d_in[3];
  const float* ln2_b = (const float*)d_in[4];
  const float* W1 = (const float*)d_in[5];
  const float* b1 = (const float*)d_in[6];
  const float* W2 = (const float*)d_in[7];
  const float* b2 = (const float*)d_in[8];
  float* out = (float*)d_out;
  char* ws = (char*)d_ws;

  const size_t MB = 1048576;
  __bf16* xb = (__bf16*)ws;                  // @0   16 MB
  __bf16* attn_b = (__bf16*)(ws + 16 * MB);  // @16  16 MB (also ff partial 0)
  __bf16* ffb = attn_b;
  __bf16* ff1b = (__bf16*)(ws + 32 * MB);    // @32  16 MB (ff partial 1)
  __bf16* w1t = (__bf16*)(ws + 48 * MB);     // @48  8 MB
  __bf16* w2t = (__bf16*)(ws + 56 * MB);     // @56  8 MB
  __bf16* hbuf = (__bf16*)(ws + 64 * MB);    // @64  Mc*4096*2 B

  int Mc = 8192;
  while (Mc > 512 && 64 * MB + (size_t)Mc * 8192 > ws_size) Mc >>= 1;

  transpose_cvt<<<dim3(4096 / 64, 1024 / 64), 256, 0, stream>>>(W1, w1t, 1024, 4096);
  transpose_cvt<<<dim3(1024 / 64, 4096 / 64), 256, 0, stream>>>(W2, w2t, 4096, 1024);
  attn_kernel<<<1024, 256, 0, stream>>>(src, attn_b);
  ln1_kernel<<<8192, 256, 0, stream>>>(src, attn_b, ln1_g, ln1_b, xb);
  for (int m0 = 0; m0 < 8192; m0 += Mc) {
    gemm8p<0><<<dim3((Mc / 256) * (4096 / 256), 1), 512, 0, stream>>>(
        xb + (size_t)m0 * 1024, w1t, b1, hbuf, 0, Mc, 4096, 1024, 1024);
    gemm8p<1><<<dim3((Mc / 256) * (1024 / 256), 2), 512, 0, stream>>>(
        hbuf, w2t, nullptr, ffb + (size_t)m0 * 1024, (size_t)8192 * 1024,
        Mc, 1024, 4096, 2048);
  }
  ln2_kernel<<<8192, 256, 0, stream>>>(xb, ffb, ff1b, b2, ln2_g, ln2_b, out);
}

// Round 14
// 226.789 us; speedup vs baseline: 1.0772x; 1.0162x over previous
//
#include <hip/hip_runtime.h>

typedef __bf16 bf16x8 __attribute__((ext_vector_type(8)));
typedef __bf16 bf16x4 __attribute__((ext_vector_type(4)));
typedef float f32x4 __attribute__((ext_vector_type(4)));

#define MFMA16(a, b, c) __builtin_amdgcn_mfma_f32_16x16x32_bf16((a), (b), (c), 0, 0, 0)

__device__ __forceinline__ void gload_lds16(const void* g, void* l) {
  __builtin_amdgcn_global_load_lds(
      (const __attribute__((address_space(1))) unsigned int*)g,
      (__attribute__((address_space(3))) unsigned int*)l, 16, 0, 0);
}

// ---------------------------------------------------------------------------
// src f32 -> bf16 (one pass; feeds attn K/V staging). 16 elems/thread.
// ---------------------------------------------------------------------------
__global__ __launch_bounds__(256) void cvt_bf16(const float* __restrict__ in,
                                                __bf16* __restrict__ out) {
  const size_t i = ((size_t)blockIdx.x * 256 + threadIdx.x) * 16;
  const float4 a = *(const float4*)(in + i);
  const float4 b = *(const float4*)(in + i + 4);
  const float4 c = *(const float4*)(in + i + 8);
  const float4 d = *(const float4*)(in + i + 12);
  bf16x8 lo, hi;
  lo[0] = (__bf16)a.x; lo[1] = (__bf16)a.y; lo[2] = (__bf16)a.z; lo[3] = (__bf16)a.w;
  lo[4] = (__bf16)b.x; lo[5] = (__bf16)b.y; lo[6] = (__bf16)b.z; lo[7] = (__bf16)b.w;
  hi[0] = (__bf16)c.x; hi[1] = (__bf16)c.y; hi[2] = (__bf16)c.z; hi[3] = (__bf16)c.w;
  hi[4] = (__bf16)d.x; hi[5] = (__bf16)d.y; hi[6] = (__bf16)d.z; hi[7] = (__bf16)d.w;
  *(bf16x8*)(out + i) = lo;
  *(bf16x8*)(out + i + 8) = hi;
}

// ---------------------------------------------------------------------------
// Sliding-window attention (round 13 structure) + this round: K/V staged from
// pre-converted bf16 (sb) — zero per-tile converts, no OOB selects (clamped
// rows are finite; the window mask provably neutralizes every OOB key).
// Q still read from f32 src (once per block, full precision).
// ---------------------------------------------------------------------------
__global__ __launch_bounds__(256, 2) void attn_kernel(const float* __restrict__ src,
                                                      const __bf16* __restrict__ sb,
                                                      __bf16* __restrict__ attn_out) {
  const int bid = blockIdx.x;
  const int half = bid & 1;
  const int c = (bid >> 1) & 15;
  const int h = (bid >> 5) & 15;
  const int b = bid >> 9;
  const int tid = threadIdx.x;
  const int w = tid >> 6;
  const int lane = tid & 63;
  const int lg = lane >> 4;
  const int l16 = lane & 15;
  const size_t b4096 = (size_t)b * 4096;

  __shared__ __bf16 Ks[2][64][72];
  __shared__ __bf16 Vt[2][64][72];

  const int q0 = c * 256 + half * 128 + w * 32;
  const float LOG2E = 1.44269504f;

  bf16x8 qf[2][2];
#pragma unroll
  for (int qfi = 0; qfi < 2; ++qfi)
#pragma unroll
    for (int ks = 0; ks < 2; ++ks) {
      const int row = q0 + qfi * 16 + l16;
      const int d0 = ks * 32 + lg * 8;
      const float* p = src + (b4096 + row) * 1024 + h * 64 + d0;
      bf16x8 v;
#pragma unroll
      for (int j = 0; j < 8; ++j) v[j] = (__bf16)(p[j] * LOG2E);
      qf[qfi][ks] = v;
    }

  int krow[4];
#pragma unroll
  for (int kf = 0; kf < 4; ++kf)
    krow[kf] = ((kf >> 1) << 5) + ((l16 >> 2) << 3) + ((kf & 1) << 2) + (l16 & 3);

  const f32x4 z4 = {0.f, 0.f, 0.f, 0.f};
  float m_run[2], l_run[2];
  f32x4 o[2][4];
#pragma unroll
  for (int qfi = 0; qfi < 2; ++qfi) {
    m_run[qfi] = -6.0e8f;
    l_run[qfi] = 0.f;
#pragma unroll
    for (int df = 0; df < 4; ++df) o[qfi][df] = z4;
  }

  const int stage_key = tid >> 2;
  const int d0a = (tid & 3) * 16;
  const int vcolA = stage_key ^ d0a;
  const int vcolB = stage_key ^ (d0a + 8);

  int kpos = c * 256 - 256 + stage_key;
  bf16x8 kvA, kvB;
  {
    const int rc = min(max(kpos, 0), 4095);
    const __bf16* p = sb + (b4096 + rc) * 1024 + h * 64 + d0a;
    kvA = *(const bf16x8*)p;
    kvB = *(const bf16x8*)(p + 8);
  }

  for (int kt = 0; kt < 12; ++kt) {
    const int kbase = c * 256 - 256 + kt * 64;
    const int cur = kt & 1;

    *(bf16x8*)&Ks[cur][stage_key][d0a] = kvA;
    *(bf16x8*)&Ks[cur][stage_key][d0a + 8] = kvB;
#pragma unroll
    for (int j = 0; j < 8; ++j) Vt[cur][d0a + j][vcolA] = kvA[j];
#pragma unroll
    for (int j = 0; j < 8; ++j) Vt[cur][d0a + 8 + j][vcolB] = kvB[j];
    asm volatile("s_waitcnt lgkmcnt(0)" ::: "memory");
    __builtin_amdgcn_s_barrier();
    __builtin_amdgcn_sched_barrier(0);

    kpos += 64;
    if (kt < 11) {
      const int rc = min(max(kpos, 0), 4095);
      const __bf16* p = sb + (b4096 + rc) * 1024 + h * 64 + d0a;
      kvA = *(const bf16x8*)p;
      kvB = *(const bf16x8*)(p + 8);
    }

    const bool skip = (kbase + 63 < 0) | (kbase >= 4096) |
                      (kbase + 63 < q0 - 256) | (kbase > q0 + 31 + 256);
    if (skip) continue;

    f32x4 s[4][2];
#pragma unroll
    for (int kf = 0; kf < 4; ++kf)
#pragma unroll
      for (int qfi = 0; qfi < 2; ++qfi) s[kf][qfi] = z4;

#pragma unroll
    for (int ks = 0; ks < 2; ++ks) {
      bf16x8 ka[4];
#pragma unroll
      for (int kf = 0; kf < 4; ++kf)
        ka[kf] = *(const bf16x8*)&Ks[cur][krow[kf]][ks * 32 + lg * 8];
#pragma unroll
      for (int kf = 0; kf < 4; ++kf)
#pragma unroll
        for (int qfi = 0; qfi < 2; ++qfi)
          s[kf][qfi] = MFMA16(ka[kf], qf[qfi][ks], s[kf][qfi]);
    }

    // mask covers every tile containing an OOB or out-of-window key; K/V
    // values for those keys are finite garbage (clamped rows) -> P becomes 0.
    const bool needmask = (kbase < 0) | (kbase > 4032) |
                          (kbase < q0 - 225) | (kbase > q0 + 193);
    if (needmask) {
#pragma unroll
      for (int qfi = 0; qfi < 2; ++qfi) {
        const int qp = q0 + qfi * 16 + l16;
#pragma unroll
        for (int kf = 0; kf < 4; ++kf) {
          const int kb0 = kbase + ((kf >> 1) << 5) + 8 * lg + ((kf & 1) << 2);
#pragma unroll
          for (int reg = 0; reg < 4; ++reg) {
            const int kp = kb0 + reg;
            const int rel = kp - qp;
            if (rel > 256 || rel < -256 || kp < 0 || kp >= 4096)
              s[kf][qfi][reg] = -1e9f;
          }
        }
      }
    }

    bf16x4 pb[4][2];
#pragma unroll
    for (int qfi = 0; qfi < 2; ++qfi) {
      float tm = s[0][qfi][0];
#pragma unroll
      for (int kf = 0; kf < 4; ++kf)
#pragma unroll
        for (int reg = 0; reg < 4; ++reg) tm = fmaxf(tm, s[kf][qfi][reg]);
      tm = fmaxf(tm, __shfl_xor(tm, 16, 64));
      tm = fmaxf(tm, __shfl_xor(tm, 32, 64));

      const bool nomax = __all(tm <= m_run[qfi] + 8.f);
      float scl = 1.f;
      if (!nomax) {
        const float mn = fmaxf(m_run[qfi], tm);
        scl = exp2f(m_run[qfi] - mn);
        m_run[qfi] = mn;
#pragma unroll
        for (int df = 0; df < 4; ++df)
#pragma unroll
          for (int reg = 0; reg < 4; ++reg) o[qfi][df][reg] *= scl;
      }
      const float mn = m_run[qfi];

      float rs = 0.f;
#pragma unroll
      for (int kf = 0; kf < 4; ++kf) {
        bf16x4 pv;
#pragma unroll
        for (int reg = 0; reg < 4; ++reg) {
          const float p = exp2f(s[kf][qfi][reg] - mn);
          rs += p;
          pv[reg] = (__bf16)p;
        }
        pb[kf][qfi] = pv;
      }
      rs += __shfl_xor(rs, 16, 64);
      rs += __shfl_xor(rs, 32, 64);
      l_run[qfi] = l_run[qfi] * scl + rs;
    }

#pragma unroll
    for (int ks2 = 0; ks2 < 2; ++ks2) {
      bf16x8 av[4];
#pragma unroll
      for (int df = 0; df < 4; ++df) {
        const int d = df * 16 + l16;
        const int blk = (ks2 * 4 + lg) ^ (d >> 3);
        av[df] = *(const bf16x8*)&Vt[cur][d][blk * 8];
      }
#pragma unroll
      for (int qfi = 0; qfi < 2; ++qfi) {
        const bf16x8 bq = __builtin_shufflevector(pb[2 * ks2][qfi], pb[2 * ks2 + 1][qfi],
                                                  0, 1, 2, 3, 4, 5, 6, 7);
#pragma unroll
        for (int df = 0; df < 4; ++df)
          o[qfi][df] = MFMA16(av[df], bq, o[qfi][df]);
      }
    }
  }

#pragma unroll
  for (int qfi = 0; qfi < 2; ++qfi) {
    const float inv = 1.0f / l_run[qfi];
    const int qp = q0 + qfi * 16 + l16;
    __bf16* dst = attn_out + (b4096 + qp) * 1024 + h * 64 + lg * 4;
#pragma unroll
    for (int df = 0; df < 4; ++df) {
      bf16x4 y;
      y[0] = (__bf16)(o[qfi][df][0] * inv);
      y[1] = (__bf16)(o[qfi][df][1] * inv);
      y[2] = (__bf16)(o[qfi][df][2] * inv);
      y[3] = (__bf16)(o[qfi][df][3] * inv);
      *(bf16x4*)&dst[df * 16] = y;
    }
  }
}

// ---------------------------------------------------------------------------
// m201-faithful 8-phase NT GEMM (round 13, best measured — unchanged).
// ---------------------------------------------------------------------------
template <int MODE>
__global__ __launch_bounds__(512, 2) void gemm8p(const __bf16* __restrict__ A,
                                                 const __bf16* __restrict__ Bt,
                                                 const float* __restrict__ bias,
                                                 __bf16* __restrict__ out,
                                                 size_t ksplit_stride,
                                                 int M, int N, int Kstride, int Klen) {
  __shared__ char smem[131072];
  const int tid = threadIdx.x;
  const int w = tid >> 6;
  const int lane = tid & 63;
  const int lg = lane >> 4;
  const int l16 = lane & 15;
  const int wr = w >> 2;
  const int wc = w & 3;

  const int nbn = N >> 8;
  const int x = ((int)blockIdx.x & 7) * ((int)gridDim.x >> 3) + ((int)blockIdx.x >> 3);
  const long bm = (long)(x / nbn) * 256;
  const long bn = (long)(x % nbn) * 256;
  const long koff = (long)blockIdx.y * Klen;
  out += (size_t)blockIdx.y * ksplit_stride;

  const f32x4 z4 = {0.f, 0.f, 0.f, 0.f};
  f32x4 acc[8][4];
#pragma unroll
  for (int i = 0; i < 8; ++i)
#pragma unroll
    for (int j = 0; j < 4; ++j) acc[i][j] = z4;

  const int srow = tid >> 3;
  const int g0 = (tid & 7) ^ (srow & 7);
  const __bf16* Ag = A + (size_t)(bm + srow) * Kstride + koff + g0 * 8;
  const __bf16* Bg = Bt + (size_t)(bn + srow) * Kstride + koff + g0 * 8;
  char* ldst = smem + (w << 10);

  auto stage = [&](int kt, int which) {
    const __bf16* s = ((which & 2) ? Bg : Ag) +
                      (size_t)((which & 1) * 128) * Kstride + (size_t)kt * 64;
    char* d = ldst + ((kt & 1) << 16) + ((which & 2) << 14) + ((which & 1) << 14);
    gload_lds16(s, d);
    gload_lds16(s + (size_t)64 * Kstride, d + 8192);
  };

  const unsigned rsw = (unsigned)((l16 & 7) << 4);
  const char* pA = smem + wr * 16384 + l16 * 128;
  const char* pB = smem + 32768 + (wc >> 1) * 16384 + ((wc & 1) * 64 + l16) * 128;
  auto rdA = [&](int sel, int rf, int ks) {
    return *(const bf16x8*)(pA + (sel << 16) + rf * 2048 +
                            ((unsigned)((ks << 6) | (lg << 4)) ^ rsw));
  };
  auto rdB = [&](int sel, int cf, int ks) {
    return *(const bf16x8*)(pB + (sel << 16) + cf * 2048 +
                            ((unsigned)((ks << 6) | (lg << 4)) ^ rsw));
  };

  const int NT = Klen >> 6;

  stage(0, 0); stage(0, 1); stage(0, 2); stage(0, 3);
  stage(1, 2); stage(1, 3);
  asm volatile("s_waitcnt vmcnt(4)" ::: "memory");
  __builtin_amdgcn_s_barrier();
  __builtin_amdgcn_sched_barrier(0);

  bf16x8 af[4][2], bl[2][2], bh[2][2];

  for (int i = 0; i < (NT >> 1); ++i) {
    const int a = i << 1;
    const int b = a + 1, c2 = a + 2, d2 = a + 3;
    const bool more = (c2 < NT);

#pragma unroll
    for (int sel = 0; sel < 2; ++sel) {
      const int tnext = sel ? d2 : c2;
      const int anext = sel ? c2 : b;
      const bool stA = sel ? more : true;
      const bool stB = more;

#pragma unroll
      for (int rf = 0; rf < 4; ++rf)
#pragma unroll
        for (int ks = 0; ks < 2; ++ks) af[rf][ks] = rdA(sel, rf, ks);
#pragma unroll
      for (int cf = 0; cf < 2; ++cf)
#pragma unroll
        for (int ks = 0; ks < 2; ++ks) bl[cf][ks] = rdB(sel, cf, ks);
      if (stA) stage(anext, 0);
      __builtin_amdgcn_s_barrier();
      asm volatile("s_waitcnt lgkmcnt(0)" ::: "memory");
      __builtin_amdgcn_sched_barrier(0);
      __builtin_amdgcn_s_setprio(1);
#pragma unroll
      for (int rf = 0; rf < 4; ++rf)
#pragma unroll
        for (int cf = 0; cf < 2; ++cf)
#pragma unroll
          for (int ks = 0; ks < 2; ++ks)
            acc[rf][cf] = MFMA16(af[rf][ks], bl[cf][ks], acc[rf][cf]);
      __builtin_amdgcn_s_setprio(0);

#pragma unroll
      for (int cf = 0; cf < 2; ++cf)
#pragma unroll
        for (int ks = 0; ks < 2; ++ks) bh[cf][ks] = rdB(sel, 2 + cf, ks);
      if (stA) stage(anext, 1);
      __builtin_amdgcn_s_barrier();
      asm volatile("s_waitcnt lgkmcnt(0)" ::: "memory");
      __builtin_amdgcn_sched_barrier(0);
      __builtin_amdgcn_s_setprio(1);
#pragma unroll
      for (int rf = 0; rf < 4; ++rf)
#pragma unroll
        for (int cf = 0; cf < 2; ++cf)
#pragma unroll
          for (int ks = 0; ks < 2; ++ks)
            acc[rf][2 + cf] = MFMA16(af[rf][ks], bh[cf][ks], acc[rf][2 + cf]);
      __builtin_amdgcn_s_setprio(0);

#pragma unroll
      for (int rf = 0; rf < 4; ++rf)
#pragma unroll
        for (int ks = 0; ks < 2; ++ks) af[rf][ks] = rdA(sel, 4 + rf, ks);
      if (stB) stage(tnext, 2);
      __builtin_amdgcn_s_barrier();
      asm volatile("s_waitcnt lgkmcnt(0)" ::: "memory");
      __builtin_amdgcn_sched_barrier(0);
      __builtin_amdgcn_s_setprio(1);
#pragma unroll
      for (int rf = 0; rf < 4; ++rf)
#pragma unroll
        for (int cf = 0; cf < 2; ++cf)
#pragma unroll
          for (int ks = 0; ks < 2; ++ks)
            acc[4 + rf][cf] = MFMA16(af[rf][ks], bl[cf][ks], acc[4 + rf][cf]);
      __builtin_amdgcn_s_setprio(0);

      if (stB) {
        stage(tnext, 3);
        asm volatile("s_waitcnt vmcnt(4)" ::: "memory");
      } else {
        asm volatile("s_waitcnt vmcnt(0)" ::: "memory");
      }
      __builtin_amdgcn_s_barrier();
      __builtin_amdgcn_sched_barrier(0);
      __builtin_amdgcn_s_setprio(1);
#pragma unroll
      for (int rf = 0; rf < 4; ++rf)
#pragma unroll
        for (int cf = 0; cf < 2; ++cf)
#pragma unroll
          for (int ks = 0; ks < 2; ++ks)
            acc[4 + rf][2 + cf] = MFMA16(af[rf][ks], bh[cf][ks], acc[4 + rf][2 + cf]);
      __builtin_amdgcn_s_setprio(0);
    }
  }

  float bv[4];
  if (MODE == 0) {
#pragma unroll
    for (int cf = 0; cf < 4; ++cf) bv[cf] = bias[bn + wc * 64 + cf * 16 + l16];
  }
#pragma unroll
  for (int rf = 0; rf < 8; ++rf)
#pragma unroll
    for (int reg = 0; reg < 4; ++reg) {
      const long row = bm + wr * 128 + rf * 16 + lg * 4 + reg;
#pragma unroll
      for (int cf = 0; cf < 4; ++cf) {
        const long col = bn + wc * 64 + cf * 16 + l16;
        if (MODE == 0) {
          out[row * N + col] = (__bf16)fmaxf(acc[rf][cf][reg] + bv[cf], 0.f);
        } else {
          out[row * N + col] = (__bf16)acc[rf][cf][reg];
        }
      }
    }
}

// ---------------------------------------------------------------------------
__global__ __launch_bounds__(256) void transpose_cvt(const float* __restrict__ in,
                                                     __bf16* __restrict__ out,
                                                     int R, int C) {
  __shared__ float tile[64][65];
  const long r0 = (long)blockIdx.y * 64;
  const long c0 = (long)blockIdx.x * 64;
  const int t = threadIdx.x;
  const int tr = t >> 6;
  const int tc = t & 63;
#pragma unroll
  for (int i = 0; i < 16; ++i) {
    const int r = tr * 16 + i;
    tile[r][tc] = in[(r0 + r) * C + c0 + tc];
  }
  __syncthreads();
#pragma unroll
  for (int i = 0; i < 16; ++i) {
    const int cc = tr * 16 + i;
    out[(c0 + cc) * (long)R + r0 + tc] = (__bf16)tile[tc][cc];
  }
}

// ---------------------------------------------------------------------------
__global__ __launch_bounds__(256) void ln1_kernel(const float* __restrict__ src,
                                                  const __bf16* __restrict__ attn,
                                                  const float* __restrict__ g,
                                                  const float* __restrict__ bta,
                                                  __bf16* __restrict__ xb) {
  const long r = blockIdx.x;
  const int t = threadIdx.x;
  const float4 a = *(const float4*)&src[r * 1024 + t * 4];
  const bf16x4 cc = *(const bf16x4*)&attn[r * 1024 + t * 4];
  float v[4] = {a.x + (float)cc[0], a.y + (float)cc[1],
                a.z + (float)cc[2], a.w + (float)cc[3]};
  float s = v[0] + v[1] + v[2] + v[3];
  float s2 = v[0] * v[0] + v[1] * v[1] + v[2] * v[2] + v[3] * v[3];
#pragma unroll
  for (int off = 32; off >= 1; off >>= 1) {
    s += __shfl_xor(s, off, 64);
    s2 += __shfl_xor(s2, off, 64);
  }
  __shared__ float red[8];
  if ((t & 63) == 0) { red[t >> 6] = s; red[(t >> 6) + 4] = s2; }
  __syncthreads();
  s = red[0] + red[1] + red[2] + red[3];
  s2 = red[4] + red[5] + red[6] + red[7];
  const float mu = s * (1.f / 1024.f);
  const float var = s2 * (1.f / 1024.f) - mu * mu;
  const float rstd = rsqrtf(var + 1e-5f);
  const float4 gv = *(const float4*)&g[t * 4];
  const float4 bv = *(const float4*)&bta[t * 4];
  bf16x4 y;
  y[0] = (__bf16)((v[0] - mu) * rstd * gv.x + bv.x);
  y[1] = (__bf16)((v[1] - mu) * rstd * gv.y + bv.y);
  y[2] = (__bf16)((v[2] - mu) * rstd * gv.z + bv.z);
  y[3] = (__bf16)((v[3] - mu) * rstd * gv.w + bv.w);
  *(bf16x4*)&xb[r * 1024 + t * 4] = y;
}

__global__ __launch_bounds__(256) void ln2_kernel(const __bf16* __restrict__ xb,
                                                  const __bf16* __restrict__ f0,
                                                  const __bf16* __restrict__ f1,
                                                  const float* __restrict__ b2,
                                                  const float* __restrict__ g,
                                                  const float* __restrict__ bta,
                                                  float* __restrict__ out) {
  const long r = blockIdx.x;
  const int t = threadIdx.x;
  const bf16x4 xv = *(const bf16x4*)&xb[r * 1024 + t * 4];
  const bf16x4 f0v = *(const bf16x4*)&f0[r * 1024 + t * 4];
  const bf16x4 f1v = *(const bf16x4*)&f1[r * 1024 + t * 4];
  const float4 b2v = *(const float4*)&b2[t * 4];
  float v[4];
#pragma unroll
  for (int i = 0; i < 4; ++i)
    v[i] = (float)xv[i] + (float)f0v[i] + (float)f1v[i] +
           ((const float*)&b2v)[i];
  float s = v[0] + v[1] + v[2] + v[3];
  float s2 = v[0] * v[0] + v[1] * v[1] + v[2] * v[2] + v[3] * v[3];
#pragma unroll
  for (int off = 32; off >= 1; off >>= 1) {
    s += __shfl_xor(s, off, 64);
    s2 += __shfl_xor(s2, off, 64);
  }
  __shared__ float red[8];
  if ((t & 63) == 0) { red[t >> 6] = s; red[(t >> 6) + 4] = s2; }
  __syncthreads();
  s = red[0] + red[1] + red[2] + red[3];
  s2 = red[4] + red[5] + red[6] + red[7];
  const float mu = s * (1.f / 1024.f);
  const float var = s2 * (1.f / 1024.f) - mu * mu;
  const float rstd = rsqrtf(var + 1e-5f);
  const float4 gv = *(const float4*)&g[t * 4];
  const float4 bv = *(const float4*)&bta[t * 4];
  float4 y;
  y.x = (v[0] - mu) * rstd * gv.x + bv.x;
  y.y = (v[1] - mu) * rstd * gv.y + bv.y;
  y.z = (v[2] - mu) * rstd * gv.z + bv.z;
  y.w = (v[3] - mu) * rstd * gv.w + bv.w;
  *(float4*)&out[r * 1024 + t * 4] = y;
}

// ---------------------------------------------------------------------------
extern "C" void kernel_launch(void* const* d_in, const int* in_sizes, int n_in,
                              void* d_out, int out_size, void* d_ws, size_t ws_size,
                              hipStream_t stream) {
  const float* src = (const float*)d_in[0];
  const float* ln1_g = (const float*)d_in[1];
  const float* ln1_b = (const float*)d_in[2];
  const float* ln2_g = (const float*)d_in[3];
  const float* ln2_b = (const float*)d_in[4];
  const float* W1 = (const float*)d_in[5];
  const float* b1 = (const float*)d_in[6];
  const float* W2 = (const float*)d_in[7];
  const float* b2 = (const float*)d_in[8];
  float* out = (float*)d_out;
  char* ws = (char*)d_ws;

  const size_t MB = 1048576;
  __bf16* xb = (__bf16*)ws;                  // @0   16 MB
  __bf16* attn_b = (__bf16*)(ws + 16 * MB);  // @16  16 MB (also ff partial 0)
  __bf16* ffb = attn_b;
  __bf16* ff1b = (__bf16*)(ws + 32 * MB);    // @32  16 MB (ff partial 1)
  __bf16* w1t = (__bf16*)(ws + 48 * MB);     // @48  8 MB
  __bf16* w2t = (__bf16*)(ws + 56 * MB);     // @56  8 MB
  __bf16* sb = (__bf16*)(ws + 64 * MB);      // @64  16 MB (src as bf16)
  __bf16* hbuf = (__bf16*)(ws + 80 * MB);    // @80  Mc*4096*2 B

  int Mc = 8192;
  while (Mc > 512 && 80 * MB + (size_t)Mc * 8192 > ws_size) Mc >>= 1;

  cvt_bf16<<<2048, 256, 0, stream>>>(src, sb);
  transpose_cvt<<<dim3(4096 / 64, 1024 / 64), 256, 0, stream>>>(W1, w1t, 1024, 4096);
  transpose_cvt<<<dim3(1024 / 64, 4096 / 64), 256, 0, stream>>>(W2, w2t, 4096, 1024);
  attn_kernel<<<1024, 256, 0, stream>>>(src, sb, attn_b);
  ln1_kernel<<<8192, 256, 0, stream>>>(src, attn_b, ln1_g, ln1_b, xb);
  for (int m0 = 0; m0 < 8192; m0 += Mc) {
    gemm8p<0><<<dim3((Mc / 256) * (4096 / 256), 1), 512, 0, stream>>>(
        xb + (size_t)m0 * 1024, w1t, b1, hbuf, 0, Mc, 4096, 1024, 1024);
    gemm8p<1><<<dim3((Mc / 256) * (1024 / 256), 2), 512, 0, stream>>>(
        hbuf, w2t, nullptr, ffb + (size_t)m0 * 1024, (size_t)8192 * 1024,
        Mc, 1024, 4096, 2048);
  }
  ln2_kernel<<<8192, 256, 0, stream>>>(xb, ffb, ff1b, b2, ln2_g, ln2_b, out);
}

// Round 15
// 224.507 us; speedup vs baseline: 1.0882x; 1.0102x over previous
//
#include <hip/hip_runtime.h>

typedef __bf16 bf16x8 __attribute__((ext_vector_type(8)));
typedef __bf16 bf16x4 __attribute__((ext_vector_type(4)));
typedef float f32x4 __attribute__((ext_vector_type(4)));

#define MFMA16(a, b, c) __builtin_amdgcn_mfma_f32_16x16x32_bf16((a), (b), (c), 0, 0, 0)

__device__ __forceinline__ void gload_lds16(const void* g, void* l) {
  __builtin_amdgcn_global_load_lds(
      (const __attribute__((address_space(1))) unsigned int*)g,
      (__attribute__((address_space(3))) unsigned int*)l, 16, 0, 0);
}

// ---------------------------------------------------------------------------
// src f32 -> bf16 (one pass; feeds attn Q/K/V staging). 16 elems/thread.
// ---------------------------------------------------------------------------
__global__ __launch_bounds__(256) void cvt_bf16(const float* __restrict__ in,
                                                __bf16* __restrict__ out) {
  const size_t i = ((size_t)blockIdx.x * 256 + threadIdx.x) * 16;
  const float4 a = *(const float4*)(in + i);
  const float4 b = *(const float4*)(in + i + 4);
  const float4 c = *(const float4*)(in + i + 8);
  const float4 d = *(const float4*)(in + i + 12);
  bf16x8 lo, hi;
  lo[0] = (__bf16)a.x; lo[1] = (__bf16)a.y; lo[2] = (__bf16)a.z; lo[3] = (__bf16)a.w;
  lo[4] = (__bf16)b.x; lo[5] = (__bf16)b.y; lo[6] = (__bf16)b.z; lo[7] = (__bf16)b.w;
  hi[0] = (__bf16)c.x; hi[1] = (__bf16)c.y; hi[2] = (__bf16)c.z; hi[3] = (__bf16)c.w;
  hi[4] = (__bf16)d.x; hi[5] = (__bf16)d.y; hi[6] = (__bf16)d.z; hi[7] = (__bf16)d.w;
  *(bf16x8*)(out + i) = lo;
  *(bf16x8*)(out + i + 8) = hi;
}

// ---------------------------------------------------------------------------
// Sliding-window attention (round 14 structure) + this round: exact-window
// tiling — each half only sweeps its 10 needed K-tiles (kt in [2*half,
// 2*half+10)); half=0 covers keys [c256-256, c256+384), half=1 covers
// [c256-128, c256+512). Q also read from pre-converted bf16 (sb).
// ---------------------------------------------------------------------------
__global__ __launch_bounds__(256, 2) void attn_kernel(const __bf16* __restrict__ sb,
                                                      __bf16* __restrict__ attn_out) {
  const int bid = blockIdx.x;
  const int half = bid & 1;
  const int c = (bid >> 1) & 15;
  const int h = (bid >> 5) & 15;
  const int b = bid >> 9;
  const int tid = threadIdx.x;
  const int w = tid >> 6;
  const int lane = tid & 63;
  const int lg = lane >> 4;
  const int l16 = lane & 15;
  const size_t b4096 = (size_t)b * 4096;

  __shared__ __bf16 Ks[2][64][72];
  __shared__ __bf16 Vt[2][64][72];

  const int q0 = c * 256 + half * 128 + w * 32;
  const float LOG2E = 1.44269504f;

  bf16x8 qf[2][2];
#pragma unroll
  for (int qfi = 0; qfi < 2; ++qfi)
#pragma unroll
    for (int ks = 0; ks < 2; ++ks) {
      const int row = q0 + qfi * 16 + l16;
      const int d0 = ks * 32 + lg * 8;
      const bf16x8 raw = *(const bf16x8*)(sb + (b4096 + row) * 1024 + h * 64 + d0);
      bf16x8 v;
#pragma unroll
      for (int j = 0; j < 8; ++j) v[j] = (__bf16)((float)raw[j] * LOG2E);
      qf[qfi][ks] = v;
    }

  int krow[4];
#pragma unroll
  for (int kf = 0; kf < 4; ++kf)
    krow[kf] = ((kf >> 1) << 5) + ((l16 >> 2) << 3) + ((kf & 1) << 2) + (l16 & 3);

  const f32x4 z4 = {0.f, 0.f, 0.f, 0.f};
  float m_run[2], l_run[2];
  f32x4 o[2][4];
#pragma unroll
  for (int qfi = 0; qfi < 2; ++qfi) {
    m_run[qfi] = -6.0e8f;
    l_run[qfi] = 0.f;
#pragma unroll
    for (int df = 0; df < 4; ++df) o[qfi][df] = z4;
  }

  const int stage_key = tid >> 2;
  const int d0a = (tid & 3) * 16;
  const int vcolA = stage_key ^ d0a;
  const int vcolB = stage_key ^ (d0a + 8);

  const int kt0 = half * 2;           // exact-window: 10 tiles per half
  const int ktend = kt0 + 10;
  int kpos = c * 256 - 256 + kt0 * 64 + stage_key;
  bf16x8 kvA, kvB;
  {
    const int rc = min(max(kpos, 0), 4095);
    const __bf16* p = sb + (b4096 + rc) * 1024 + h * 64 + d0a;
    kvA = *(const bf16x8*)p;
    kvB = *(const bf16x8*)(p + 8);
  }

  for (int kt = kt0; kt < ktend; ++kt) {
    const int kbase = c * 256 - 256 + kt * 64;
    const int cur = kt & 1;

    *(bf16x8*)&Ks[cur][stage_key][d0a] = kvA;
    *(bf16x8*)&Ks[cur][stage_key][d0a + 8] = kvB;
#pragma unroll
    for (int j = 0; j < 8; ++j) Vt[cur][d0a + j][vcolA] = kvA[j];
#pragma unroll
    for (int j = 0; j < 8; ++j) Vt[cur][d0a + 8 + j][vcolB] = kvB[j];
    asm volatile("s_waitcnt lgkmcnt(0)" ::: "memory");
    __builtin_amdgcn_s_barrier();
    __builtin_amdgcn_sched_barrier(0);

    kpos += 64;
    if (kt < ktend - 1) {
      const int rc = min(max(kpos, 0), 4095);
      const __bf16* p = sb + (b4096 + rc) * 1024 + h * 64 + d0a;
      kvA = *(const bf16x8*)p;
      kvB = *(const bf16x8*)(p + 8);
    }

    const bool skip = (kbase + 63 < 0) | (kbase >= 4096) |
                      (kbase + 63 < q0 - 256) | (kbase > q0 + 31 + 256);
    if (skip) continue;

    f32x4 s[4][2];
#pragma unroll
    for (int kf = 0; kf < 4; ++kf)
#pragma unroll
      for (int qfi = 0; qfi < 2; ++qfi) s[kf][qfi] = z4;

#pragma unroll
    for (int ks = 0; ks < 2; ++ks) {
      bf16x8 ka[4];
#pragma unroll
      for (int kf = 0; kf < 4; ++kf)
        ka[kf] = *(const bf16x8*)&Ks[cur][krow[kf]][ks * 32 + lg * 8];
#pragma unroll
      for (int kf = 0; kf < 4; ++kf)
#pragma unroll
        for (int qfi = 0; qfi < 2; ++qfi)
          s[kf][qfi] = MFMA16(ka[kf], qf[qfi][ks], s[kf][qfi]);
    }

    const bool needmask = (kbase < 0) | (kbase > 4032) |
                          (kbase < q0 - 225) | (kbase > q0 + 193);
    if (needmask) {
#pragma unroll
      for (int qfi = 0; qfi < 2; ++qfi) {
        const int qp = q0 + qfi * 16 + l16;
#pragma unroll
        for (int kf = 0; kf < 4; ++kf) {
          const int kb0 = kbase + ((kf >> 1) << 5) + 8 * lg + ((kf & 1) << 2);
#pragma unroll
          for (int reg = 0; reg < 4; ++reg) {
            const int kp = kb0 + reg;
            const int rel = kp - qp;
            if (rel > 256 || rel < -256 || kp < 0 || kp >= 4096)
              s[kf][qfi][reg] = -1e9f;
          }
        }
      }
    }

    bf16x4 pb[4][2];
#pragma unroll
    for (int qfi = 0; qfi < 2; ++qfi) {
      float tm = s[0][qfi][0];
#pragma unroll
      for (int kf = 0; kf < 4; ++kf)
#pragma unroll
        for (int reg = 0; reg < 4; ++reg) tm = fmaxf(tm, s[kf][qfi][reg]);
      tm = fmaxf(tm, __shfl_xor(tm, 16, 64));
      tm = fmaxf(tm, __shfl_xor(tm, 32, 64));

      const bool nomax = __all(tm <= m_run[qfi] + 8.f);
      float scl = 1.f;
      if (!nomax) {
        const float mn = fmaxf(m_run[qfi], tm);
        scl = exp2f(m_run[qfi] - mn);
        m_run[qfi] = mn;
#pragma unroll
        for (int df = 0; df < 4; ++df)
#pragma unroll
          for (int reg = 0; reg < 4; ++reg) o[qfi][df][reg] *= scl;
      }
      const float mn = m_run[qfi];

      float rs = 0.f;
#pragma unroll
      for (int kf = 0; kf < 4; ++kf) {
        bf16x4 pv;
#pragma unroll
        for (int reg = 0; reg < 4; ++reg) {
          const float p = exp2f(s[kf][qfi][reg] - mn);
          rs += p;
          pv[reg] = (__bf16)p;
        }
        pb[kf][qfi] = pv;
      }
      rs += __shfl_xor(rs, 16, 64);
      rs += __shfl_xor(rs, 32, 64);
      l_run[qfi] = l_run[qfi] * scl + rs;
    }

#pragma unroll
    for (int ks2 = 0; ks2 < 2; ++ks2) {
      bf16x8 av[4];
#pragma unroll
      for (int df = 0; df < 4; ++df) {
        const int d = df * 16 + l16;
        const int blk = (ks2 * 4 + lg) ^ (d >> 3);
        av[df] = *(const bf16x8*)&Vt[cur][d][blk * 8];
      }
#pragma unroll
      for (int qfi = 0; qfi < 2; ++qfi) {
        const bf16x8 bq = __builtin_shufflevector(pb[2 * ks2][qfi], pb[2 * ks2 + 1][qfi],
                                                  0, 1, 2, 3, 4, 5, 6, 7);
#pragma unroll
        for (int df = 0; df < 4; ++df)
          o[qfi][df] = MFMA16(av[df], bq, o[qfi][df]);
      }
    }
  }

#pragma unroll
  for (int qfi = 0; qfi < 2; ++qfi) {
    const float inv = 1.0f / l_run[qfi];
    const int qp = q0 + qfi * 16 + l16;
    __bf16* dst = attn_out + (b4096 + qp) * 1024 + h * 64 + lg * 4;
#pragma unroll
    for (int df = 0; df < 4; ++df) {
      bf16x4 y;
      y[0] = (__bf16)(o[qfi][df][0] * inv);
      y[1] = (__bf16)(o[qfi][df][1] * inv);
      y[2] = (__bf16)(o[qfi][df][2] * inv);
      y[3] = (__bf16)(o[qfi][df][3] * inv);
      *(bf16x4*)&dst[df * 16] = y;
    }
  }
}

// ---------------------------------------------------------------------------
// m201-faithful 8-phase NT GEMM (round 13, best measured — unchanged).
// ---------------------------------------------------------------------------
template <int MODE>
__global__ __launch_bounds__(512, 2) void gemm8p(const __bf16* __restrict__ A,
                                                 const __bf16* __restrict__ Bt,
                                                 const float* __restrict__ bias,
                                                 __bf16* __restrict__ out,
                                                 size_t ksplit_stride,
                                                 int M, int N, int Kstride, int Klen) {
  __shared__ char smem[131072];
  const int tid = threadIdx.x;
  const int w = tid >> 6;
  const int lane = tid & 63;
  const int lg = lane >> 4;
  const int l16 = lane & 15;
  const int wr = w >> 2;
  const int wc = w & 3;

  const int nbn = N >> 8;
  const int x = ((int)blockIdx.x & 7) * ((int)gridDim.x >> 3) + ((int)blockIdx.x >> 3);
  const long bm = (long)(x / nbn) * 256;
  const long bn = (long)(x % nbn) * 256;
  const long koff = (long)blockIdx.y * Klen;
  out += (size_t)blockIdx.y * ksplit_stride;

  const f32x4 z4 = {0.f, 0.f, 0.f, 0.f};
  f32x4 acc[8][4];
#pragma unroll
  for (int i = 0; i < 8; ++i)
#pragma unroll
    for (int j = 0; j < 4; ++j) acc[i][j] = z4;

  const int srow = tid >> 3;
  const int g0 = (tid & 7) ^ (srow & 7);
  const __bf16* Ag = A + (size_t)(bm + srow) * Kstride + koff + g0 * 8;
  const __bf16* Bg = Bt + (size_t)(bn + srow) * Kstride + koff + g0 * 8;
  char* ldst = smem + (w << 10);

  auto stage = [&](int kt, int which) {
    const __bf16* s = ((which & 2) ? Bg : Ag) +
                      (size_t)((which & 1) * 128) * Kstride + (size_t)kt * 64;
    char* d = ldst + ((kt & 1) << 16) + ((which & 2) << 14) + ((which & 1) << 14);
    gload_lds16(s, d);
    gload_lds16(s + (size_t)64 * Kstride, d + 8192);
  };

  const unsigned rsw = (unsigned)((l16 & 7) << 4);
  const char* pA = smem + wr * 16384 + l16 * 128;
  const char* pB = smem + 32768 + (wc >> 1) * 16384 + ((wc & 1) * 64 + l16) * 128;
  auto rdA = [&](int sel, int rf, int ks) {
    return *(const bf16x8*)(pA + (sel << 16) + rf * 2048 +
                            ((unsigned)((ks << 6) | (lg << 4)) ^ rsw));
  };
  auto rdB = [&](int sel, int cf, int ks) {
    return *(const bf16x8*)(pB + (sel << 16) + cf * 2048 +
                            ((unsigned)((ks << 6) | (lg << 4)) ^ rsw));
  };

  const int NT = Klen >> 6;

  stage(0, 0); stage(0, 1); stage(0, 2); stage(0, 3);
  stage(1, 2); stage(1, 3);
  asm volatile("s_waitcnt vmcnt(4)" ::: "memory");
  __builtin_amdgcn_s_barrier();
  __builtin_amdgcn_sched_barrier(0);

  bf16x8 af[4][2], bl[2][2], bh[2][2];

  for (int i = 0; i < (NT >> 1); ++i) {
    const int a = i << 1;
    const int b = a + 1, c2 = a + 2, d2 = a + 3;
    const bool more = (c2 < NT);

#pragma unroll
    for (int sel = 0; sel < 2; ++sel) {
      const int tnext = sel ? d2 : c2;
      const int anext = sel ? c2 : b;
      const bool stA = sel ? more : true;
      const bool stB = more;

#pragma unroll
      for (int rf = 0; rf < 4; ++rf)
#pragma unroll
        for (int ks = 0; ks < 2; ++ks) af[rf][ks] = rdA(sel, rf, ks);
#pragma unroll
      for (int cf = 0; cf < 2; ++cf)
#pragma unroll
        for (int ks = 0; ks < 2; ++ks) bl[cf][ks] = rdB(sel, cf, ks);
      if (stA) stage(anext, 0);
      __builtin_amdgcn_s_barrier();
      asm volatile("s_waitcnt lgkmcnt(0)" ::: "memory");
      __builtin_amdgcn_sched_barrier(0);
      __builtin_amdgcn_s_setprio(1);
#pragma unroll
      for (int rf = 0; rf < 4; ++rf)
#pragma unroll
        for (int cf = 0; cf < 2; ++cf)
#pragma unroll
          for (int ks = 0; ks < 2; ++ks)
            acc[rf][cf] = MFMA16(af[rf][ks], bl[cf][ks], acc[rf][cf]);
      __builtin_amdgcn_s_setprio(0);

#pragma unroll
      for (int cf = 0; cf < 2; ++cf)
#pragma unroll
        for (int ks = 0; ks < 2; ++ks) bh[cf][ks] = rdB(sel, 2 + cf, ks);
      if (stA) stage(anext, 1);
      __builtin_amdgcn_s_barrier();
      asm volatile("s_waitcnt lgkmcnt(0)" ::: "memory");
      __builtin_amdgcn_sched_barrier(0);
      __builtin_amdgcn_s_setprio(1);
#pragma unroll
      for (int rf = 0; rf < 4; ++rf)
#pragma unroll
        for (int cf = 0; cf < 2; ++cf)
#pragma unroll
          for (int ks = 0; ks < 2; ++ks)
            acc[rf][2 + cf] = MFMA16(af[rf][ks], bh[cf][ks], acc[rf][2 + cf]);
      __builtin_amdgcn_s_setprio(0);

#pragma unroll
      for (int rf = 0; rf < 4; ++rf)
#pragma unroll
        for (int ks = 0; ks < 2; ++ks) af[rf][ks] = rdA(sel, 4 + rf, ks);
      if (stB) stage(tnext, 2);
      __builtin_amdgcn_s_barrier();
      asm volatile("s_waitcnt lgkmcnt(0)" ::: "memory");
      __builtin_amdgcn_sched_barrier(0);
      __builtin_amdgcn_s_setprio(1);
#pragma unroll
      for (int rf = 0; rf < 4; ++rf)
#pragma unroll
        for (int cf = 0; cf < 2; ++cf)
#pragma unroll
          for (int ks = 0; ks < 2; ++ks)
            acc[4 + rf][cf] = MFMA16(af[rf][ks], bl[cf][ks], acc[4 + rf][cf]);
      __builtin_amdgcn_s_setprio(0);

      if (stB) {
        stage(tnext, 3);
        asm volatile("s_waitcnt vmcnt(4)" ::: "memory");
      } else {
        asm volatile("s_waitcnt vmcnt(0)" ::: "memory");
      }
      __builtin_amdgcn_s_barrier();
      __builtin_amdgcn_sched_barrier(0);
      __builtin_amdgcn_s_setprio(1);
#pragma unroll
      for (int rf = 0; rf < 4; ++rf)
#pragma unroll
        for (int cf = 0; cf < 2; ++cf)
#pragma unroll
          for (int ks = 0; ks < 2; ++ks)
            acc[4 + rf][2 + cf] = MFMA16(af[rf][ks], bh[cf][ks], acc[4 + rf][2 + cf]);
      __builtin_amdgcn_s_setprio(0);
    }
  }

  float bv[4];
  if (MODE == 0) {
#pragma unroll
    for (int cf = 0; cf < 4; ++cf) bv[cf] = bias[bn + wc * 64 + cf * 16 + l16];
  }
#pragma unroll
  for (int rf = 0; rf < 8; ++rf)
#pragma unroll
    for (int reg = 0; reg < 4; ++reg) {
      const long row = bm + wr * 128 + rf * 16 + lg * 4 + reg;
#pragma unroll
      for (int cf = 0; cf < 4; ++cf) {
        const long col = bn + wc * 64 + cf * 16 + l16;
        if (MODE == 0) {
          out[row * N + col] = (__bf16)fmaxf(acc[rf][cf][reg] + bv[cf], 0.f);
        } else {
          out[row * N + col] = (__bf16)acc[rf][cf][reg];
        }
      }
    }
}

// ---------------------------------------------------------------------------
__global__ __launch_bounds__(256) void transpose_cvt(const float* __restrict__ in,
                                                     __bf16* __restrict__ out,
                                                     int R, int C) {
  __shared__ float tile[64][65];
  const long r0 = (long)blockIdx.y * 64;
  const long c0 = (long)blockIdx.x * 64;
  const int t = threadIdx.x;
  const int tr = t >> 6;
  const int tc = t & 63;
#pragma unroll
  for (int i = 0; i < 16; ++i) {
    const int r = tr * 16 + i;
    tile[r][tc] = in[(r0 + r) * C + c0 + tc];
  }
  __syncthreads();
#pragma unroll
  for (int i = 0; i < 16; ++i) {
    const int cc = tr * 16 + i;
    out[(c0 + cc) * (long)R + r0 + tc] = (__bf16)tile[tc][cc];
  }
}

// ---------------------------------------------------------------------------
__global__ __launch_bounds__(256) void ln1_kernel(const float* __restrict__ src,
                                                  const __bf16* __restrict__ attn,
                                                  const float* __restrict__ g,
                                                  const float* __restrict__ bta,
                                                  __bf16* __restrict__ xb) {
  const long r = blockIdx.x;
  const int t = threadIdx.x;
  const float4 a = *(const float4*)&src[r * 1024 + t * 4];
  const bf16x4 cc = *(const bf16x4*)&attn[r * 1024 + t * 4];
  float v[4] = {a.x + (float)cc[0], a.y + (float)cc[1],
                a.z + (float)cc[2], a.w + (float)cc[3]};
  float s = v[0] + v[1] + v[2] + v[3];
  float s2 = v[0] * v[0] + v[1] * v[1] + v[2] * v[2] + v[3] * v[3];
#pragma unroll
  for (int off = 32; off >= 1; off >>= 1) {
    s += __shfl_xor(s, off, 64);
    s2 += __shfl_xor(s2, off, 64);
  }
  __shared__ float red[8];
  if ((t & 63) == 0) { red[t >> 6] = s; red[(t >> 6) + 4] = s2; }
  __syncthreads();
  s = red[0] + red[1] + red[2] + red[3];
  s2 = red[4] + red[5] + red[6] + red[7];
  const float mu = s * (1.f / 1024.f);
  const float var = s2 * (1.f / 1024.f) - mu * mu;
  const float rstd = rsqrtf(var + 1e-5f);
  const float4 gv = *(const float4*)&g[t * 4];
  const float4 bv = *(const float4*)&bta[t * 4];
  bf16x4 y;
  y[0] = (__bf16)((v[0] - mu) * rstd * gv.x + bv.x);
  y[1] = (__bf16)((v[1] - mu) * rstd * gv.y + bv.y);
  y[2] = (__bf16)((v[2] - mu) * rstd * gv.z + bv.z);
  y[3] = (__bf16)((v[3] - mu) * rstd * gv.w + bv.w);
  *(bf16x4*)&xb[r * 1024 + t * 4] = y;
}

__global__ __launch_bounds__(256) void ln2_kernel(const __bf16* __restrict__ xb,
                                                  const __bf16* __restrict__ f0,
                                                  const __bf16* __restrict__ f1,
                                                  const float* __restrict__ b2,
                                                  const float* __restrict__ g,
                                                  const float* __restrict__ bta,
                                                  float* __restrict__ out) {
  const long r = blockIdx.x;
  const int t = threadIdx.x;
  const bf16x4 xv = *(const bf16x4*)&xb[r * 1024 + t * 4];
  const bf16x4 f0v = *(const bf16x4*)&f0[r * 1024 + t * 4];
  const bf16x4 f1v = *(const bf16x4*)&f1[r * 1024 + t * 4];
  const float4 b2v = *(const float4*)&b2[t * 4];
  float v[4];
#pragma unroll
  for (int i = 0; i < 4; ++i)
    v[i] = (float)xv[i] + (float)f0v[i] + (float)f1v[i] +
           ((const float*)&b2v)[i];
  float s = v[0] + v[1] + v[2] + v[3];
  float s2 = v[0] * v[0] + v[1] * v[1] + v[2] * v[2] + v[3] * v[3];
#pragma unroll
  for (int off = 32; off >= 1; off >>= 1) {
    s += __shfl_xor(s, off, 64);
    s2 += __shfl_xor(s2, off, 64);
  }
  __shared__ float red[8];
  if ((t & 63) == 0) { red[t >> 6] = s; red[(t >> 6) + 4] = s2; }
  __syncthreads();
  s = red[0] + red[1] + red[2] + red[3];
  s2 = red[4] + red[5] + red[6] + red[7];
  const float mu = s * (1.f / 1024.f);
  const float var = s2 * (1.f / 1024.f) - mu * mu;
  const float rstd = rsqrtf(var + 1e-5f);
  const float4 gv = *(const float4*)&g[t * 4];
  const float4 bv = *(const float4*)&bta[t * 4];
  float4 y;
  y.x = (v[0] - mu) * rstd * gv.x + bv.x;
  y.y = (v[1] - mu) * rstd * gv.y + bv.y;
  y.z = (v[2] - mu) * rstd * gv.z + bv.z;
  y.w = (v[3] - mu) * rstd * gv.w + bv.w;
  *(float4*)&out[r * 1024 + t * 4] = y;
}

// ---------------------------------------------------------------------------
extern "C" void kernel_launch(void* const* d_in, const int* in_sizes, int n_in,
                              void* d_out, int out_size, void* d_ws, size_t ws_size,
                              hipStream_t stream) {
  const float* src = (const float*)d_in[0];
  const float* ln1_g = (const float*)d_in[1];
  const float* ln1_b = (const float*)d_in[2];
  const float* ln2_g = (const float*)d_in[3];
  const float* ln2_b = (const float*)d_in[4];
  const float* W1 = (const float*)d_in[5];
  const float* b1 = (const float*)d_in[6];
  const float* W2 = (const float*)d_in[7];
  const float* b2 = (const float*)d_in[8];
  float* out = (float*)d_out;
  char* ws = (char*)d_ws;

  const size_t MB = 1048576;
  __bf16* xb = (__bf16*)ws;                  // @0   16 MB
  __bf16* attn_b = (__bf16*)(ws + 16 * MB);  // @16  16 MB (also ff partial 0)
  __bf16* ffb = attn_b;
  __bf16* ff1b = (__bf16*)(ws + 32 * MB);    // @32  16 MB (ff partial 1)
  __bf16* w1t = (__bf16*)(ws + 48 * MB);     // @48  8 MB
  __bf16* w2t = (__bf16*)(ws + 56 * MB);     // @56  8 MB
  __bf16* sb = (__bf16*)(ws + 64 * MB);      // @64  16 MB (src as bf16)
  __bf16* hbuf = (__bf16*)(ws + 80 * MB);    // @80  Mc*4096*2 B

  int Mc = 8192;
  while (Mc > 512 && 80 * MB + (size_t)Mc * 8192 > ws_size) Mc >>= 1;

  cvt_bf16<<<2048, 256, 0, stream>>>(src, sb);
  transpose_cvt<<<dim3(4096 / 64, 1024 / 64), 256, 0, stream>>>(W1, w1t, 1024, 4096);
  transpose_cvt<<<dim3(1024 / 64, 4096 / 64), 256, 0, stream>>>(W2, w2t, 4096, 1024);
  attn_kernel<<<1024, 256, 0, stream>>>(sb, attn_b);
  ln1_kernel<<<8192, 256, 0, stream>>>(src, attn_b, ln1_g, ln1_b, xb);
  for (int m0 = 0; m0 < 8192; m0 += Mc) {
    gemm8p<0><<<dim3((Mc / 256) * (4096 / 256), 1), 512, 0, stream>>>(
        xb + (size_t)m0 * 1024, w1t, b1, hbuf, 0, Mc, 4096, 1024, 1024);
    gemm8p<1><<<dim3((Mc / 256) * (1024 / 256), 2), 512, 0, stream>>>(
        hbuf, w2t, nullptr, ffb + (size_t)m0 * 1024, (size_t)8192 * 1024,
        Mc, 1024, 4096, 2048);
  }
  ln2_kernel<<<8192, 256, 0, stream>>>(xb, ffb, ff1b, b2, ln2_g, ln2_b, out);
}